// Round 8
// baseline (241.131 us; speedup 1.0000x reference)
//
#include <hip/hip_runtime.h>

// ---------------------------------------------------------------------------
// LinearAttention (Taylor feature map), MI355X/gfx950.
// Inputs: FLOAT32 (runtime-probed; bf16 copies in ws). Outputs: FLOAT32
// [out (4,2048,1024) | kv_state (4,16,1,64,273)].
//
// r14: akv merge reverted (71us vs ~60 serial; dispatch-order co-residency
// assumption failed). attn: one task per block -> grid (8,64) = 512 blocks
// = 2 blocks/CU (16 waves/CU, 2x TLP vs r10's 8); dynamic scheduling
// absorbs the per-task load spread; all 8 tasks of a bh on one XCD.
// kv_mfma standalone again (grid (4,64)). gemm_nt kept at r13 (BK=64,
// chunked XCD swizzle, both-sides XOR LDS swizzle).
// ---------------------------------------------------------------------------

typedef unsigned short u16;
typedef unsigned int u32;
typedef __attribute__((ext_vector_type(4))) float f32x4;
typedef __attribute__((ext_vector_type(16))) float f32x16;
typedef __attribute__((ext_vector_type(8))) short s16x8;

struct MaskT { static constexpr bool value = true;  };
struct MaskF { static constexpr bool value = false; };

__device__ __forceinline__ float bf2f(u16 u) {
    union { unsigned int i; float f; } x; x.i = ((unsigned int)u) << 16; return x.f;
}
__device__ __forceinline__ u16 f2bf(float f) {
    union { float f; unsigned int u; } x; x.f = f;
    unsigned int r = x.u + 0x7FFFu + ((x.u >> 16) & 1u);
    return (u16)(r >> 16);
}

typedef const __attribute__((address_space(1))) u32* gas1_t;
typedef __attribute__((address_space(3))) u32* las3_t;
__device__ __forceinline__ void gld16(const u16* g, u16* l) {
    __builtin_amdgcn_global_load_lds((gas1_t)(const void*)g, (las3_t)(void*)l, 16, 0, 0);
}

// ---------------- input dtype probe + fused convert -------------------------
__global__ void detect_kernel(const unsigned int* __restrict__ H, int* __restrict__ flag)
{
    const int lane = threadIdx.x;
    int cnt = 0;
#pragma unroll
    for (int i = 0; i < 16; ++i) {
        const unsigned int wrd = H[lane * 16 + i];
        const int e = (int)((wrd >> 7) & 0xFFu);
        if (e >= 85 && e <= 170) ++cnt;
    }
    cnt += __shfl_xor(cnt, 1);  cnt += __shfl_xor(cnt, 2);
    cnt += __shfl_xor(cnt, 4);  cnt += __shfl_xor(cnt, 8);
    cnt += __shfl_xor(cnt, 16); cnt += __shfl_xor(cnt, 32);
    if (lane == 0) *flag = (cnt < 700) ? 1 : 0;    // 1 = inputs are f32
}

// All 6 tensors in one grid-strided, float4-vectorized kernel.
__global__ __launch_bounds__(256)
void cvt_all_kernel(const void* __restrict__ H,  const void* __restrict__ Wq,
                    const void* __restrict__ Wk, const void* __restrict__ Wv,
                    const void* __restrict__ Wo, const void* __restrict__ gw,
                    u16* __restrict__ Hb,  u16* __restrict__ Wqb,
                    u16* __restrict__ Wkb, u16* __restrict__ Wvb,
                    u16* __restrict__ Wob, u16* __restrict__ gwb,
                    const int* __restrict__ flag)
{
    const int f32in = *flag;
    const int NQ = 11010112 / 4;                 // total quads
    for (int qi = blockIdx.x * 256 + threadIdx.x; qi < NQ; qi += gridDim.x * 256) {
        const int i = qi * 4;
        const void* src; u16* dst; int off;
        if      (i <  8388608) { src = H;  dst = Hb;  off = i; }
        else if (i <  8650752) { src = Wq; dst = Wqb; off = i - 8388608; }
        else if (i <  8912896) { src = Wk; dst = Wkb; off = i - 8650752; }
        else if (i <  9961472) { src = Wv; dst = Wvb; off = i - 8912896; }
        else if (i < 11010048) { src = Wo; dst = Wob; off = i - 9961472; }
        else                   { src = gw; dst = gwb; off = i - 11010048; }
        ushort4 o;
        if (f32in) {
            const float4 v = *((const float4*)src + (off >> 2));
            o.x = f2bf(v.x); o.y = f2bf(v.y); o.z = f2bf(v.z); o.w = f2bf(v.w);
        } else {
            o = *((const ushort4*)src + (off >> 2));
        }
        *(ushort4*)(dst + off) = o;
    }
}

// ---------------- GEMM: C = A(8192,1024) . B(N,1024)^T, bf16 in, f32 acc ----
// BK=64: LDS [128][64] per matrix (32KB total), 16 K-steps, 2 barriers each.
// Both-sides XOR swizzle: G[row][seg^(row&7)] stored at LDS[row][seg]
// (pre-swizzled gld_lds source); ds_read at seg=(kk*4+qd)^(row&7).
// Chunked XCD swizzle on the grid. MODE 0: fused QKV; MODE 1: f32 out.
template<int MODE>
__global__ __launch_bounds__(256)
void gemm_nt(const u16* __restrict__ A,
             const u16* __restrict__ Bq, const u16* __restrict__ Bk,
             const u16* __restrict__ Bv,
             u16* __restrict__ Oq, u16* __restrict__ Ok,
             u16* __restrict__ Ovt, float* __restrict__ Of)
{
    __shared__ __attribute__((aligned(16))) u16 As[8192];   // 128 x 64
    __shared__ __attribute__((aligned(16))) u16 Bs[8192];
    const int t = threadIdx.x;
    const int lane = t & 63, w = t >> 6;
    const int c = lane & 15, qd = lane >> 4;
    const int wm = (w >> 1) * 64, wn = (w & 1) * 64;
    // chunked XCD swizzle: XCD x gets contiguous lid chunk (L2-fit panels)
    const int nwgx = gridDim.x;
    const int pid = blockIdx.y * nwgx + blockIdx.x;
    const int lid = (pid & 7) * ((nwgx * 64) >> 3) + (pid >> 3);
    const int rm = (lid / nwgx) * 128;
    const int cb = (lid % nwgx) * 128;

    const u16* Bsrc; int wrow0;
    if (MODE == 0) {
        if (cb < 256)      { Bsrc = Bq; wrow0 = cb; }
        else if (cb < 512) { Bsrc = Bk; wrow0 = cb - 256; }
        else               { Bsrc = Bv; wrow0 = cb - 512; }
    } else { Bsrc = Bq; wrow0 = cb; }

    f32x4 acc[4][4];
#pragma unroll
    for (int i = 0; i < 4; ++i)
#pragma unroll
        for (int j = 0; j < 4; ++j) acc[i][j] = (f32x4){0.f, 0.f, 0.f, 0.f};

    // staging: 4 issues per matrix per K-step; issue i covers rows [i*32,i*32+32)
    const int r0 = w * 8 + (lane >> 3);
    const int s0 = (lane & 7) ^ (lane >> 3);        // row&7 == lane>>3 here
    const u16* Ag = A    + (size_t)(rm    + r0) * 1024 + s0 * 8;
    const u16* Bg = Bsrc + (size_t)(wrow0 + r0) * 1024 + s0 * 8;
    u16* AsW = As + w * 512;    // wave-uniform LDS base (lane*16B added by HW)
    u16* BsW = Bs + w * 512;

    for (int kt = 0; kt < 16; ++kt) {
        const int k0 = kt * 64;
        __syncthreads();                        // prior readers done
#pragma unroll
        for (int i = 0; i < 4; ++i) {
            gld16(Ag + (size_t)(i * 32) * 1024 + k0, AsW + i * 2048);
            gld16(Bg + (size_t)(i * 32) * 1024 + k0, BsW + i * 2048);
        }
        __syncthreads();                        // drains vmcnt, joins waves
        s16x8 af[2][4], bfr[2][4];
#pragma unroll
        for (int kk = 0; kk < 2; ++kk) {
#pragma unroll
            for (int mt = 0; mt < 4; ++mt) {
                const int row = wm + mt * 16 + c;
                af[kk][mt] = *(const s16x8*)&As[row * 64 + (((kk * 4 + qd) ^ (row & 7)) * 8)];
            }
#pragma unroll
            for (int nt = 0; nt < 4; ++nt) {
                const int row = wn + nt * 16 + c;
                bfr[kk][nt] = *(const s16x8*)&Bs[row * 64 + (((kk * 4 + qd) ^ (row & 7)) * 8)];
            }
        }
#pragma unroll
        for (int kk = 0; kk < 2; ++kk)
#pragma unroll
            for (int mt = 0; mt < 4; ++mt)
#pragma unroll
                for (int nt = 0; nt < 4; ++nt)
                    acc[mt][nt] = __builtin_amdgcn_mfma_f32_16x16x32_bf16(af[kk][mt], bfr[kk][nt], acc[mt][nt], 0, 0, 0);
    }

#pragma unroll
    for (int mt = 0; mt < 4; ++mt) {
#pragma unroll
        for (int nt = 0; nt < 4; ++nt) {
            const int gc = cb + wn + nt * 16 + c;
            const int row0 = rm + wm + mt * 16 + qd * 4;
            if (MODE == 1) {
#pragma unroll
                for (int r = 0; r < 4; ++r)
                    Of[(size_t)(row0 + r) * 1024 + gc] = acc[mt][nt][r];
            } else if (gc < 512) {
#pragma unroll
                for (int r = 0; r < 4; ++r) {
                    const int row = row0 + r;
                    const int b_ = row >> 11, l_ = row & 2047;
                    const int cc = gc & 255;
                    const int h = cc >> 4, idx = cc & 15;
                    u16* dst = (gc < 256) ? Oq : Ok;
                    dst[(size_t)((b_ * 16 + h) * 2048 + l_) * 16 + idx] = f2bf(acc[mt][nt][r]);
                }
            } else {
                // V -> vt [b,h,64,l], r-consecutive => packed b64 store
                const int cc = gc - 512;
                const int h = cc >> 6, idx = cc & 63;
                const int b_ = row0 >> 11, l0 = row0 & 2047;
                ushort4 pk;
                pk.x = f2bf(acc[mt][nt][0]);
                pk.y = f2bf(acc[mt][nt][1]);
                pk.z = f2bf(acc[mt][nt][2]);
                pk.w = f2bf(acc[mt][nt][3]);
                *(ushort4*)(Ovt + ((size_t)((b_ * 16 + h) * 64 + idx)) * 2048 + l0) = pk;
            }
        }
    }
}

// ---------------- causal phi-attention + fused RMSNorm ----------------------
// ONE task (256-query tile) per block; grid (8,64) = 512 blocks = 2/CU
// (16 waves/CU). Task qb from (jj,pass): pass0 -> 7-jj, pass1 -> jj; all 8
// tasks of a bh on one XCD. Per 128-key chunk: stage V (dbuf, swizzled-src
// gld_lds, 1 barrier), K frags dense from global (prefetched), QK^T via
// 32x32x16 (S^T), phi in-reg, cvt_pk+permlane32_swap -> PV in-reg A-frags,
// PV B-frags via conflict-free swizzled ds_read_b128. RMSNorm fused.
__global__ __launch_bounds__(512, 4)
void attn_kernel(const u16* __restrict__ Qg, const u16* __restrict__ Kg,
                 const u16* __restrict__ Vt, const u16* __restrict__ gwb,
                 u16* __restrict__ Yn)
{
    __shared__ __attribute__((aligned(16))) u16 Vs[2][8192];   // 2 x 16 KB
    const int t = threadIdx.x, lane = t & 63, w = t >> 6;
    const int la = lane & 31, h = lane >> 5;
    const int pid = blockIdx.y * 8 + blockIdx.x;
    const int x = pid & 7;                       // XCD (blocks round-robin)
    const int yy = pid >> 3;                     // 0..63
    const int bh = x * 8 + (yy >> 3);
    const int jj = yy & 3;
    const int pass = (yy >> 2) & 1;
    const int qb = pass ? jj : (7 - jj);         // this block's 256-query tile
    const int b_ = bh >> 4, hh = bh & 15;
    const u16* Qh = Qg + (size_t)bh * (2048 * 16);
    const u16* Kh = Kg + (size_t)bh * (2048 * 16);
    const u16* Vh = Vt + (size_t)bh * (64 * 2048);
    const float gl0 = bf2f(gwb[la]);
    const float gl1 = bf2f(gwb[32 + la]);
    const f32x16 z16 = {0.f,0.f,0.f,0.f,0.f,0.f,0.f,0.f,
                        0.f,0.f,0.f,0.f,0.f,0.f,0.f,0.f};
    const int vbase0 = (la << 8) | (h << 4);     // V-frag lds byte base (ft=0)
    const int vsw = (la & 7) << 4;               // XOR swizzle bits

    auto stageV = [&](int n0s, int bufsel) {
#pragma unroll
        for (int i = 0; i < 2; ++i) {
            const int slot = i * 512 + t;
            const int fl = slot >> 4;
            const int seg = (slot & 15) ^ (fl & 7);   // pre-swizzled source
            gld16(Vh + (size_t)fl * 2048 + n0s + seg * 8,
                  (u16*)Vs[bufsel] + (size_t)(i * 512 + (w << 6)) * 8);
        }
    };

    const int q0 = qb * 256 + w * 32;        // wave's first query
    const int kf = 2 * qb + (w >> 2);        // wave's partial (diag) chunk
    const int wp = w & 3;                    // masked tile within it
    const int nck = 2 * qb + 2;              // chunks 0..nck-1

    const s16x8 bq = *(const s16x8*)(Qh + (size_t)(q0 + la) * 16 + h * 8);
    f32x16 yt0 = z16, yt1 = z16;
    s16x8 ka[4];
    const char* vsc = (const char*)Vs[0];

    auto loadK = [&](s16x8* kk, int kcL) {
#pragma unroll
        for (int kt = 0; kt < 4; ++kt)
            kk[kt] = *(const s16x8*)(Kh + (size_t)(kcL * 128 + kt * 32 + la) * 16 + h * 8);
    };

    auto tile = [&](int kt, auto MASKED) {
        constexpr bool masked = decltype(MASKED)::value;
        f32x16 sv = __builtin_amdgcn_mfma_f32_32x32x16_bf16(ka[kt], bq, z16, 0, 0, 0);
        float p[16];
#pragma unroll
        for (int r = 0; r < 16; ++r) {
            const float s = sv[r];
            float pv = fmaf(s, fmaf(s, 0.03125f, 0.25f), 1.0f);
            if (masked) {
                const int keyloc = (r & 3) + 8 * (r >> 2) + 4 * h;
                if (keyloc > la) pv = 0.f;
            }
            p[r] = pv;
        }
#pragma unroll
        for (int ks = 0; ks < 2; ++ks) {
            u32 X0, X1, Y0, Y1;
            asm("v_cvt_pk_bf16_f32 %0, %1, %2" : "=v"(X0) : "v"(p[8*ks+0]), "v"(p[8*ks+1]));
            asm("v_cvt_pk_bf16_f32 %0, %1, %2" : "=v"(X1) : "v"(p[8*ks+2]), "v"(p[8*ks+3]));
            asm("v_cvt_pk_bf16_f32 %0, %1, %2" : "=v"(Y0) : "v"(p[8*ks+4]), "v"(p[8*ks+5]));
            asm("v_cvt_pk_bf16_f32 %0, %1, %2" : "=v"(Y1) : "v"(p[8*ks+6]), "v"(p[8*ks+7]));
            // exchange halves: after swap X holds W0 (lo keys), Y holds W2
            asm("v_permlane32_swap_b32 %0, %1" : "+v"(X0), "+v"(Y0));
            asm("v_permlane32_swap_b32 %0, %1" : "+v"(X1), "+v"(Y1));
            union { uint4 u; s16x8 v; } afu;
            afu.u = (uint4){X0, X1, Y0, Y1};
            const int offb = (kt << 6) | (ks << 5);
            const s16x8 vb0 = *(const s16x8*)(vsc + (((vbase0 + offb)) ^ vsw));
            const s16x8 vb1 = *(const s16x8*)(vsc + (((vbase0 + 8192 + offb)) ^ vsw));
            yt0 = __builtin_amdgcn_mfma_f32_32x32x16_bf16(afu.v, vb0, yt0, 0, 0, 0);
            yt1 = __builtin_amdgcn_mfma_f32_32x32x16_bf16(afu.v, vb1, yt1, 0, 0, 0);
        }
    };

    // prologue: stage chunk 0, preload K(0)
    stageV(0, 0);
    loadK(ka, 0);
    __syncthreads();                         // drains gld_lds

    for (int kc = 0; kc < nck; ++kc) {
        const int cur = kc & 1;
        vsc = (const char*)Vs[cur];
        if (kc + 1 < nck) stageV((kc + 1) * 128, cur ^ 1);
        s16x8 kn[4] = {ka[0], ka[1], ka[2], ka[3]};
        if (kc < kf) loadK(kn, kc + 1);      // prefetch next K frags

        if (kc < kf) {
            tile(0, MaskF{}); tile(1, MaskF{});
            tile(2, MaskF{}); tile(3, MaskF{});
        } else if (kc == kf) {
            if (wp == 0)      { tile(0, MaskT{}); }
            else if (wp == 1) { tile(0, MaskF{}); tile(1, MaskT{}); }
            else if (wp == 2) { tile(0, MaskF{}); tile(1, MaskF{}); tile(2, MaskT{}); }
            else              { tile(0, MaskF{}); tile(1, MaskF{}); tile(2, MaskF{}); tile(3, MaskT{}); }
        }
        __syncthreads();                     // drains vmcnt: next V staged
#pragma unroll
        for (int kt = 0; kt < 4; ++kt) ka[kt] = kn[kt];
    }

    // ---- fused RMSNorm + store yn [b,l,1024] ----
#pragma unroll
    for (int r = 0; r < 16; ++r) {
        float ss = yt0[r] * yt0[r] + yt1[r] * yt1[r];
        ss += __shfl_xor(ss, 1);  ss += __shfl_xor(ss, 2);
        ss += __shfl_xor(ss, 4);  ss += __shfl_xor(ss, 8);
        ss += __shfl_xor(ss, 16);
        const float rmsv = rsqrtf(ss * (1.0f / 64.0f) + 1e-5f);
        const int row = q0 + (r & 3) + 8 * (r >> 2) + 4 * h;
        u16* dst = Yn + ((size_t)(b_ * 2048 + row)) * 1024 + hh * 64;
        dst[la]      = f2bf(yt0[r] * rmsv * gl0);
        dst[32 + la] = f2bf(yt1[r] * rmsv * gl1);
    }
}

// ---------------- kv_state as MFMA GEMM -------------------------------------
// grid (4,64): 4-way key split -> 256 blocks (full GPU). Each block: 8 chunks.
__global__ __launch_bounds__(256)
void kv_mfma_kernel(const u16* __restrict__ Kg, const u16* __restrict__ Vt,
                    float* __restrict__ kvpart)
{
    __shared__ __attribute__((aligned(16))) float kS[64][20];
    __shared__ __attribute__((aligned(16))) float kT[64][20];
    __shared__ __attribute__((aligned(16))) u16 KFs[288][72];
    __shared__ __attribute__((aligned(16))) u16 Vs[64][72];
    const int t = threadIdx.x, lane = t & 63, w = t >> 6;
    const int c = lane & 15, qd = lane >> 4;
    const int ns = blockIdx.x, bh = blockIdx.y;
    const u16* Kh  = Kg + (size_t)bh * 2048 * 16;
    const u16* Vth = Vt + (size_t)bh * 64 * 2048;

    int i2a, j2a, i2b = 18, j2b = 18;
    {
        const int dd = t;
        if (dd == 0)      { i2a = 16; j2a = 17; }
        else if (dd < 17) { i2a = dd - 1; j2a = 16; }
        else              { i2a = (dd - 17) >> 4; j2a = (dd - 17) & 15; }
        if (t < 32) {
            const int d2 = 256 + t;
            if (d2 < 273) { i2b = (d2 - 17) >> 4; j2b = (d2 - 17) & 15; }
        }
    }

    f32x4 acc[4][5];
#pragma unroll
    for (int mt = 0; mt < 4; ++mt)
#pragma unroll
        for (int j = 0; j < 5; ++j) acc[mt][j] = (f32x4){0.f, 0.f, 0.f, 0.f};

    for (int ch = 0; ch < 8; ++ch) {
        const int n0 = ns * 512 + ch * 64;
        __syncthreads();
        if (t < 128) {
            const int row = t >> 1, half = t & 1;
            uint4 kv = *(const uint4*)(Kh + (size_t)(n0 + row) * 16 + half * 8);
            const u16* ke = (const u16*)&kv;
#pragma unroll
            for (int e = 0; e < 8; ++e) {
                const float f = bf2f(ke[e]);
                kS[row][half * 8 + e] = f;
                kT[row][half * 8 + e] = f * 0.17677669529663687f;
            }
        } else if (t < 192) {
            const int row = t - 128;
            kS[row][16] = 1.f;  kS[row][17] = 1.f;  kS[row][18] = 0.f;
            kT[row][16] = 0.5f; kT[row][17] = 1.f;  kT[row][18] = 0.f;
        }
        // stage V^T from vt: conflict-free b128
#pragma unroll
        for (int i = 0; i < 2; ++i) {
            const int lin = i * 256 + t;
            const int f = lin >> 3, seg = lin & 7;
            *(uint4*)&Vs[f][seg * 8] =
                *(const uint4*)(Vth + (size_t)f * 2048 + n0 + seg * 8);
        }
        __syncthreads();
        {
            unsigned int* dst = (unsigned int*)&KFs[t][0];
#pragma unroll 8
            for (int i = 0; i < 32; ++i) {
                const float v0 = kS[2 * i][i2a]     * kT[2 * i][j2a];
                const float v1 = kS[2 * i + 1][i2a] * kT[2 * i + 1][j2a];
                dst[i] = (unsigned int)f2bf(v0) | ((unsigned int)f2bf(v1) << 16);
            }
            if (t < 32) {
                unsigned int* dst2 = (unsigned int*)&KFs[256 + t][0];
#pragma unroll 8
                for (int i = 0; i < 32; ++i) {
                    const float v0 = kS[2 * i][i2b]     * kT[2 * i][j2b];
                    const float v1 = kS[2 * i + 1][i2b] * kT[2 * i + 1][j2b];
                    dst2[i] = (unsigned int)f2bf(v0) | ((unsigned int)f2bf(v1) << 16);
                }
            }
        }
        __syncthreads();
#pragma unroll
        for (int kt = 0; kt < 2; ++kt) {
            s16x8 va[4];
#pragma unroll
            for (int mt = 0; mt < 4; ++mt)
                va[mt] = *(const s16x8*)&Vs[mt * 16 + c][kt * 32 + qd * 8];
#pragma unroll
            for (int j = 0; j < 5; ++j) {
                const int dt = w + 4 * j;
                if (dt < 18) {
                    s16x8 vb = *(const s16x8*)&KFs[dt * 16 + c][kt * 32 + qd * 8];
#pragma unroll
                    for (int mt = 0; mt < 4; ++mt)
                        acc[mt][j] = __builtin_amdgcn_mfma_f32_16x16x32_bf16(va[mt], vb, acc[mt][j], 0, 0, 0);
                }
            }
        }
    }

    float* base = kvpart + ((size_t)(ns * 64 + bh) * 64) * 273;
#pragma unroll
    for (int j = 0; j < 5; ++j) {
        const int dt = w + 4 * j;
        if (dt >= 18) continue;
        const int dd = dt * 16 + c;
        if (dd >= 273) continue;
#pragma unroll
        for (int mt = 0; mt < 4; ++mt)
#pragma unroll
            for (int r = 0; r < 4; ++r) {
                const int f = mt * 16 + qd * 4 + r;
                base[f * 273 + dd] = acc[mt][j][r];
            }
    }
}

__global__ __launch_bounds__(256)
void kv_fin_kernel(const float* __restrict__ kvpart, float* __restrict__ o)
{
    const int i = blockIdx.x * 256 + threadIdx.x;
    const int S = 64 * 64 * 273;
    if (i < S)
        o[i] = kvpart[i] + kvpart[i + S] + kvpart[i + 2 * S] + kvpart[i + 3 * S];
}

// ---------------------------------------------------------------------------
extern "C" void kernel_launch(void* const* d_in, const int* in_sizes, int n_in,
                              void* d_out, int out_size, void* d_ws, size_t ws_size,
                              hipStream_t stream)
{
    const void* H  = d_in[0];
    const void* Wq = d_in[1];
    const void* Wk = d_in[2];
    const void* Wv = d_in[3];
    const void* Wo = d_in[4];
    const void* gw = d_in[5];
    float* outf = (float*)d_out;

    char* ws = (char*)d_ws;
    const size_t M = 1 << 20;
    u16*   Hb    = (u16*)(ws);                          // 16 MiB (reused as yn)
    u16*   Wqb   = (u16*)(ws + 16 * M);
    u16*   Wkb   = (u16*)(ws + 16 * M + 512 * 1024);
    u16*   Wvb   = (u16*)(ws + 17 * M);
    u16*   Wob   = (u16*)(ws + 19 * M);
    u16*   gwb   = (u16*)(ws + 21 * M);
    int*   flag  = (int*)(ws + 21 * M + 4096);
    u16*   q     = (u16*)(ws + 22 * M);                 // 4 MiB
    u16*   k     = (u16*)(ws + 26 * M);                 // 4 MiB
    u16*   vt    = (u16*)(ws + 30 * M);                 // 16 MiB [b,h,64,l]
    float* kvpart= (float*)(ws + 46 * M);               // 4 x 4.27 MiB slabs
    u16*   yn    = Hb;                                  // reuse after gemm0

    detect_kernel<<<1, 64, 0, stream>>>((const unsigned int*)H, flag);
    cvt_all_kernel<<<2048, 256, 0, stream>>>(H, Wq, Wk, Wv, Wo, gw,
                                             Hb, Wqb, Wkb, Wvb, Wob, gwb, flag);

    gemm_nt<0><<<dim3(12, 64), 256, 0, stream>>>(Hb, Wqb, Wkb, Wvb, q, k, vt, nullptr);
    attn_kernel<<<dim3(8, 64), 512, 0, stream>>>(q, k, vt, gwb, yn);
    kv_mfma_kernel<<<dim3(4, 64), 256, 0, stream>>>(k, vt, kvpart);
    kv_fin_kernel<<<4368, 256, 0, stream>>>(kvpart, outf + (size_t)8388608);
    gemm_nt<1><<<dim3(8, 64), 256, 0, stream>>>(yn, Wob, nullptr, nullptr,
                                                nullptr, nullptr, nullptr, outf);
}

// Round 9
// 228.097 us; speedup vs baseline: 1.0571x; 1.0571x over previous
//
#include <hip/hip_runtime.h>

// ---------------------------------------------------------------------------
// LinearAttention (Taylor feature map), MI355X/gfx950.
// Inputs: FLOAT32 (runtime-probed; bf16 copies in ws). Outputs: FLOAT32
// [out (4,2048,1024) | kv_state (4,16,1,64,273)].
//
// r15: dispatch count 7 -> 5 (launch gap ~10-15us each): detect folded into
// cvt_all (wave-0 probe + LDS broadcast, recomputed per block); kv_fin
// folded into gemm1 as a grid-strided float4 epilogue. attn reverted to the
// balanced task-pair structure (grid (4,64), 18 chunk-units per block) and
// the V LDS swizzle widened 3->4 bits (seg^(fl&15) stage, (la&15)<<4 read):
// kills the 4-way bank alias behind SQ_LDS_BANK_CONFLICT=2.13M (la vs la+8
// shared a slot pattern with the old 3-bit XOR). gemm_nt body = r13 (BK=64,
// chunked XCD swizzle, both-sides XOR swizzle). kv_mfma unchanged.
// ---------------------------------------------------------------------------

typedef unsigned short u16;
typedef unsigned int u32;
typedef __attribute__((ext_vector_type(4))) float f32x4;
typedef __attribute__((ext_vector_type(16))) float f32x16;
typedef __attribute__((ext_vector_type(8))) short s16x8;

struct MaskT { static constexpr bool value = true;  };
struct MaskF { static constexpr bool value = false; };

__device__ __forceinline__ float bf2f(u16 u) {
    union { unsigned int i; float f; } x; x.i = ((unsigned int)u) << 16; return x.f;
}
__device__ __forceinline__ u16 f2bf(float f) {
    union { float f; unsigned int u; } x; x.f = f;
    unsigned int r = x.u + 0x7FFFu + ((x.u >> 16) & 1u);
    return (u16)(r >> 16);
}

typedef const __attribute__((address_space(1))) u32* gas1_t;
typedef __attribute__((address_space(3))) u32* las3_t;
__device__ __forceinline__ void gld16(const u16* g, u16* l) {
    __builtin_amdgcn_global_load_lds((gas1_t)(const void*)g, (las3_t)(void*)l, 16, 0, 0);
}

// ---------------- fused dtype probe + convert (one dispatch) ----------------
// Wave 0 of every block probes H's first 1024 words (f32 vs bf16) and
// broadcasts via LDS — no cross-block dependency, detect launch removed.
__global__ __launch_bounds__(256)
void cvt_all_kernel(const void* __restrict__ H,  const void* __restrict__ Wq,
                    const void* __restrict__ Wk, const void* __restrict__ Wv,
                    const void* __restrict__ Wo, const void* __restrict__ gw,
                    u16* __restrict__ Hb,  u16* __restrict__ Wqb,
                    u16* __restrict__ Wkb, u16* __restrict__ Wvb,
                    u16* __restrict__ Wob, u16* __restrict__ gwb)
{
    __shared__ int sflag;
    const int t = threadIdx.x;
    if (t < 64) {
        const unsigned int* Hw = (const unsigned int*)H;
        int cnt = 0;
#pragma unroll
        for (int i = 0; i < 16; ++i) {
            const unsigned int wrd = Hw[t * 16 + i];
            const int e = (int)((wrd >> 7) & 0xFFu);
            if (e >= 85 && e <= 170) ++cnt;
        }
        cnt += __shfl_xor(cnt, 1);  cnt += __shfl_xor(cnt, 2);
        cnt += __shfl_xor(cnt, 4);  cnt += __shfl_xor(cnt, 8);
        cnt += __shfl_xor(cnt, 16); cnt += __shfl_xor(cnt, 32);
        if (t == 0) sflag = (cnt < 700) ? 1 : 0;   // 1 = inputs are f32
    }
    __syncthreads();
    const int f32in = sflag;

    const int NQ = 11010112 / 4;                 // total quads
    for (int qi = blockIdx.x * 256 + t; qi < NQ; qi += gridDim.x * 256) {
        const int i = qi * 4;
        const void* src; u16* dst; int off;
        if      (i <  8388608) { src = H;  dst = Hb;  off = i; }
        else if (i <  8650752) { src = Wq; dst = Wqb; off = i - 8388608; }
        else if (i <  8912896) { src = Wk; dst = Wkb; off = i - 8650752; }
        else if (i <  9961472) { src = Wv; dst = Wvb; off = i - 8912896; }
        else if (i < 11010048) { src = Wo; dst = Wob; off = i - 9961472; }
        else                   { src = gw; dst = gwb; off = i - 11010048; }
        ushort4 o;
        if (f32in) {
            const float4 v = *((const float4*)src + (off >> 2));
            o.x = f2bf(v.x); o.y = f2bf(v.y); o.z = f2bf(v.z); o.w = f2bf(v.w);
        } else {
            o = *((const ushort4*)src + (off >> 2));
        }
        *(ushort4*)(dst + off) = o;
    }
}

// ---------------- GEMM: C = A(8192,1024) . B(N,1024)^T, bf16 in, f32 acc ----
// BK=64: LDS [128][64] per matrix (32KB total), 16 K-steps, 2 barriers each.
// Both-sides XOR swizzle. Chunked XCD swizzle. MODE 0: fused QKV; MODE 1:
// f32 out + grid-strided kv_fin epilogue (Kvp 4-slab sum -> Kvo).
template<int MODE>
__global__ __launch_bounds__(256)
void gemm_nt(const u16* __restrict__ A,
             const u16* __restrict__ Bq, const u16* __restrict__ Bk,
             const u16* __restrict__ Bv,
             u16* __restrict__ Oq, u16* __restrict__ Ok,
             u16* __restrict__ Ovt, float* __restrict__ Of,
             const float* __restrict__ Kvp, float* __restrict__ Kvo)
{
    __shared__ __attribute__((aligned(16))) u16 As[8192];   // 128 x 64
    __shared__ __attribute__((aligned(16))) u16 Bs[8192];
    const int t = threadIdx.x;
    const int lane = t & 63, w = t >> 6;
    const int c = lane & 15, qd = lane >> 4;
    const int wm = (w >> 1) * 64, wn = (w & 1) * 64;
    // chunked XCD swizzle: XCD x gets contiguous lid chunk (L2-fit panels)
    const int nwgx = gridDim.x;
    const int pid = blockIdx.y * nwgx + blockIdx.x;
    const int lid = (pid & 7) * ((nwgx * 64) >> 3) + (pid >> 3);
    const int rm = (lid / nwgx) * 128;
    const int cb = (lid % nwgx) * 128;

    const u16* Bsrc; int wrow0;
    if (MODE == 0) {
        if (cb < 256)      { Bsrc = Bq; wrow0 = cb; }
        else if (cb < 512) { Bsrc = Bk; wrow0 = cb - 256; }
        else               { Bsrc = Bv; wrow0 = cb - 512; }
    } else { Bsrc = Bq; wrow0 = cb; }

    f32x4 acc[4][4];
#pragma unroll
    for (int i = 0; i < 4; ++i)
#pragma unroll
        for (int j = 0; j < 4; ++j) acc[i][j] = (f32x4){0.f, 0.f, 0.f, 0.f};

    // staging: 4 issues per matrix per K-step; issue i covers rows [i*32,i*32+32)
    const int r0 = w * 8 + (lane >> 3);
    const int s0 = (lane & 7) ^ (lane >> 3);        // row&7 == lane>>3 here
    const u16* Ag = A    + (size_t)(rm    + r0) * 1024 + s0 * 8;
    const u16* Bg = Bsrc + (size_t)(wrow0 + r0) * 1024 + s0 * 8;
    u16* AsW = As + w * 512;    // wave-uniform LDS base (lane*16B added by HW)
    u16* BsW = Bs + w * 512;

    for (int kt = 0; kt < 16; ++kt) {
        const int k0 = kt * 64;
        __syncthreads();                        // prior readers done
#pragma unroll
        for (int i = 0; i < 4; ++i) {
            gld16(Ag + (size_t)(i * 32) * 1024 + k0, AsW + i * 2048);
            gld16(Bg + (size_t)(i * 32) * 1024 + k0, BsW + i * 2048);
        }
        __syncthreads();                        // drains vmcnt, joins waves
        s16x8 af[2][4], bfr[2][4];
#pragma unroll
        for (int kk = 0; kk < 2; ++kk) {
#pragma unroll
            for (int mt = 0; mt < 4; ++mt) {
                const int row = wm + mt * 16 + c;
                af[kk][mt] = *(const s16x8*)&As[row * 64 + (((kk * 4 + qd) ^ (row & 7)) * 8)];
            }
#pragma unroll
            for (int nt = 0; nt < 4; ++nt) {
                const int row = wn + nt * 16 + c;
                bfr[kk][nt] = *(const s16x8*)&Bs[row * 64 + (((kk * 4 + qd) ^ (row & 7)) * 8)];
            }
        }
#pragma unroll
        for (int kk = 0; kk < 2; ++kk)
#pragma unroll
            for (int mt = 0; mt < 4; ++mt)
#pragma unroll
                for (int nt = 0; nt < 4; ++nt)
                    acc[mt][nt] = __builtin_amdgcn_mfma_f32_16x16x32_bf16(af[kk][mt], bfr[kk][nt], acc[mt][nt], 0, 0, 0);
    }

#pragma unroll
    for (int mt = 0; mt < 4; ++mt) {
#pragma unroll
        for (int nt = 0; nt < 4; ++nt) {
            const int gc = cb + wn + nt * 16 + c;
            const int row0 = rm + wm + mt * 16 + qd * 4;
            if (MODE == 1) {
#pragma unroll
                for (int r = 0; r < 4; ++r)
                    Of[(size_t)(row0 + r) * 1024 + gc] = acc[mt][nt][r];
            } else if (gc < 512) {
#pragma unroll
                for (int r = 0; r < 4; ++r) {
                    const int row = row0 + r;
                    const int b_ = row >> 11, l_ = row & 2047;
                    const int cc = gc & 255;
                    const int h = cc >> 4, idx = cc & 15;
                    u16* dst = (gc < 256) ? Oq : Ok;
                    dst[(size_t)((b_ * 16 + h) * 2048 + l_) * 16 + idx] = f2bf(acc[mt][nt][r]);
                }
            } else {
                // V -> vt [b,h,64,l], r-consecutive => packed b64 store
                const int cc = gc - 512;
                const int h = cc >> 6, idx = cc & 63;
                const int b_ = row0 >> 11, l0 = row0 & 2047;
                ushort4 pk;
                pk.x = f2bf(acc[mt][nt][0]);
                pk.y = f2bf(acc[mt][nt][1]);
                pk.z = f2bf(acc[mt][nt][2]);
                pk.w = f2bf(acc[mt][nt][3]);
                *(ushort4*)(Ovt + ((size_t)((b_ * 16 + h) * 64 + idx)) * 2048 + l0) = pk;
            }
        }
    }

    // ---- grid-strided kv_fin epilogue (MODE 1 only): sum 4 slabs ----
    if (MODE == 1) {
        const int S = 64 * 64 * 273;             // floats per slab
        const int NQ4 = S / 4;                   // 279552 float4
        const int NT = gridDim.x * gridDim.y * 256;
        for (int q = pid * 256 + t; q < NQ4; q += NT) {
            float4 a = ((const float4*)Kvp)[q];
            const float4 b = ((const float4*)(Kvp + S))[q];
            const float4 c2 = ((const float4*)(Kvp + 2 * S))[q];
            const float4 d = ((const float4*)(Kvp + 3 * S))[q];
            a.x += b.x + c2.x + d.x;  a.y += b.y + c2.y + d.y;
            a.z += b.z + c2.z + d.z;  a.w += b.w + c2.w + d.w;
            ((float4*)Kvo)[q] = a;
        }
    }
}

// ---------------- causal phi-attention + fused RMSNorm ----------------------
// 512 thr = 8 waves; block tile = 256 queries (wave w: 32 q). Pair (7-j, j)
// -> 18 chunks/block, perfectly balanced; grid (4,64) = 256 blocks.
// Per 128-key chunk: stage V (dbuf, 4-bit-swizzled-src gld_lds, 1 barrier),
// K frags dense from global (prefetched), QK^T via 32x32x16 (S^T), phi
// in-reg, cvt_pk+permlane32_swap -> PV A-frags in-reg, PV B-frags via
// 4-bit-swizzled ds_read_b128 (<=2-way bank alias = free). RMSNorm fused.
__global__ __launch_bounds__(512, 2)
void attn_kernel(const u16* __restrict__ Qg, const u16* __restrict__ Kg,
                 const u16* __restrict__ Vt, const u16* __restrict__ gwb,
                 u16* __restrict__ Yn)
{
    __shared__ __attribute__((aligned(16))) u16 Vs[2][8192];   // 2 x 16 KB
    const int t = threadIdx.x, lane = t & 63, w = t >> 6;
    const int la = lane & 31, h = lane >> 5;
    // XCD swizzle: 256 blocks, 8 XCDs -> XCD x serves bh [8x, 8x+8)
    const int pid = blockIdx.y * 4 + blockIdx.x;
    const int lid = (pid & 7) * 32 + (pid >> 3);
    const int bh = lid >> 2;
    const int jj = lid & 3;                      // pair index 0..3
    const int b_ = bh >> 4, hh = bh & 15;
    const u16* Qh = Qg + (size_t)bh * (2048 * 16);
    const u16* Kh = Kg + (size_t)bh * (2048 * 16);
    const u16* Vh = Vt + (size_t)bh * (64 * 2048);
    const float gl0 = bf2f(gwb[la]);
    const float gl1 = bf2f(gwb[32 + la]);
    const f32x16 z16 = {0.f,0.f,0.f,0.f,0.f,0.f,0.f,0.f,
                        0.f,0.f,0.f,0.f,0.f,0.f,0.f,0.f};
    const int vbase0 = (la << 8) | (h << 4);     // V-frag lds byte base (ft=0)
    const int vsw = (la & 15) << 4;              // 4-bit XOR swizzle

    auto stageV = [&](int n0s, int bufsel) {
#pragma unroll
        for (int i = 0; i < 2; ++i) {
            const int slot = i * 512 + t;
            const int fl = slot >> 4;
            const int seg = (slot & 15) ^ (fl & 15);  // pre-swizzled source
            gld16(Vh + (size_t)fl * 2048 + n0s + seg * 8,
                  (u16*)Vs[bufsel] + (size_t)(i * 512 + (w << 6)) * 8);
        }
    };

    for (int pass = 0; pass < 2; ++pass) {
        const int qb = pass ? jj : (7 - jj);     // 256-query tile index
        const int q0 = qb * 256 + w * 32;        // wave's first query
        const int kf = 2 * qb + (w >> 2);        // wave's partial (diag) chunk
        const int wp = w & 3;                    // masked tile within it
        const int nck = 2 * qb + 2;              // chunks 0..nck-1

        const s16x8 bq = *(const s16x8*)(Qh + (size_t)(q0 + la) * 16 + h * 8);
        f32x16 yt0 = z16, yt1 = z16;
        s16x8 ka[4];
        const char* vsc = (const char*)Vs[0];

        auto loadK = [&](s16x8* kk, int kcL) {
#pragma unroll
            for (int kt = 0; kt < 4; ++kt)
                kk[kt] = *(const s16x8*)(Kh + (size_t)(kcL * 128 + kt * 32 + la) * 16 + h * 8);
        };

        auto tile = [&](int kt, auto MASKED) {
            constexpr bool masked = decltype(MASKED)::value;
            f32x16 sv = __builtin_amdgcn_mfma_f32_32x32x16_bf16(ka[kt], bq, z16, 0, 0, 0);
            float p[16];
#pragma unroll
            for (int r = 0; r < 16; ++r) {
                const float s = sv[r];
                float pv = fmaf(s, fmaf(s, 0.03125f, 0.25f), 1.0f);
                if (masked) {
                    const int keyloc = (r & 3) + 8 * (r >> 2) + 4 * h;
                    if (keyloc > la) pv = 0.f;
                }
                p[r] = pv;
            }
#pragma unroll
            for (int ks = 0; ks < 2; ++ks) {
                u32 X0, X1, Y0, Y1;
                asm("v_cvt_pk_bf16_f32 %0, %1, %2" : "=v"(X0) : "v"(p[8*ks+0]), "v"(p[8*ks+1]));
                asm("v_cvt_pk_bf16_f32 %0, %1, %2" : "=v"(X1) : "v"(p[8*ks+2]), "v"(p[8*ks+3]));
                asm("v_cvt_pk_bf16_f32 %0, %1, %2" : "=v"(Y0) : "v"(p[8*ks+4]), "v"(p[8*ks+5]));
                asm("v_cvt_pk_bf16_f32 %0, %1, %2" : "=v"(Y1) : "v"(p[8*ks+6]), "v"(p[8*ks+7]));
                // exchange halves: after swap X holds W0 (lo keys), Y holds W2
                asm("v_permlane32_swap_b32 %0, %1" : "+v"(X0), "+v"(Y0));
                asm("v_permlane32_swap_b32 %0, %1" : "+v"(X1), "+v"(Y1));
                union { uint4 u; s16x8 v; } afu;
                afu.u = (uint4){X0, X1, Y0, Y1};
                const int offb = (kt << 6) | (ks << 5);
                const s16x8 vb0 = *(const s16x8*)(vsc + (((vbase0 + offb)) ^ vsw));
                const s16x8 vb1 = *(const s16x8*)(vsc + (((vbase0 + 8192 + offb)) ^ vsw));
                yt0 = __builtin_amdgcn_mfma_f32_32x32x16_bf16(afu.v, vb0, yt0, 0, 0, 0);
                yt1 = __builtin_amdgcn_mfma_f32_32x32x16_bf16(afu.v, vb1, yt1, 0, 0, 0);
            }
        };

        // prologue: stage chunk 0, preload K(0)
        stageV(0, 0);
        loadK(ka, 0);
        __syncthreads();                         // drains gld_lds

        for (int kc = 0; kc < nck; ++kc) {
            const int cur = kc & 1;
            vsc = (const char*)Vs[cur];
            if (kc + 1 < nck) stageV((kc + 1) * 128, cur ^ 1);
            s16x8 kn[4] = {ka[0], ka[1], ka[2], ka[3]};
            if (kc < kf) loadK(kn, kc + 1);      // prefetch next K frags

            if (kc < kf) {
                tile(0, MaskF{}); tile(1, MaskF{});
                tile(2, MaskF{}); tile(3, MaskF{});
            } else if (kc == kf) {
                if (wp == 0)      { tile(0, MaskT{}); }
                else if (wp == 1) { tile(0, MaskF{}); tile(1, MaskT{}); }
                else if (wp == 2) { tile(0, MaskF{}); tile(1, MaskF{}); tile(2, MaskT{}); }
                else              { tile(0, MaskF{}); tile(1, MaskF{}); tile(2, MaskF{}); tile(3, MaskT{}); }
            }
            __syncthreads();                     // drains vmcnt: next V staged
#pragma unroll
            for (int kt = 0; kt < 4; ++kt) ka[kt] = kn[kt];
        }

        // ---- fused RMSNorm + store yn [b,l,1024] ----
#pragma unroll
        for (int r = 0; r < 16; ++r) {
            float ss = yt0[r] * yt0[r] + yt1[r] * yt1[r];
            ss += __shfl_xor(ss, 1);  ss += __shfl_xor(ss, 2);
            ss += __shfl_xor(ss, 4);  ss += __shfl_xor(ss, 8);
            ss += __shfl_xor(ss, 16);
            const float rmsv = rsqrtf(ss * (1.0f / 64.0f) + 1e-5f);
            const int row = q0 + (r & 3) + 8 * (r >> 2) + 4 * h;
            u16* dst = Yn + ((size_t)(b_ * 2048 + row)) * 1024 + hh * 64;
            dst[la]      = f2bf(yt0[r] * rmsv * gl0);
            dst[32 + la] = f2bf(yt1[r] * rmsv * gl1);
        }
    }
}

// ---------------- kv_state as MFMA GEMM -------------------------------------
// grid (4,64): 4-way key split -> 256 blocks (full GPU). Each block: 8 chunks.
__global__ __launch_bounds__(256)
void kv_mfma_kernel(const u16* __restrict__ Kg, const u16* __restrict__ Vt,
                    float* __restrict__ kvpart)
{
    __shared__ __attribute__((aligned(16))) float kS[64][20];
    __shared__ __attribute__((aligned(16))) float kT[64][20];
    __shared__ __attribute__((aligned(16))) u16 KFs[288][72];
    __shared__ __attribute__((aligned(16))) u16 Vs[64][72];
    const int t = threadIdx.x, lane = t & 63, w = t >> 6;
    const int c = lane & 15, qd = lane >> 4;
    const int ns = blockIdx.x, bh = blockIdx.y;
    const u16* Kh  = Kg + (size_t)bh * 2048 * 16;
    const u16* Vth = Vt + (size_t)bh * 64 * 2048;

    int i2a, j2a, i2b = 18, j2b = 18;
    {
        const int dd = t;
        if (dd == 0)      { i2a = 16; j2a = 17; }
        else if (dd < 17) { i2a = dd - 1; j2a = 16; }
        else              { i2a = (dd - 17) >> 4; j2a = (dd - 17) & 15; }
        if (t < 32) {
            const int d2 = 256 + t;
            if (d2 < 273) { i2b = (d2 - 17) >> 4; j2b = (d2 - 17) & 15; }
        }
    }

    f32x4 acc[4][5];
#pragma unroll
    for (int mt = 0; mt < 4; ++mt)
#pragma unroll
        for (int j = 0; j < 5; ++j) acc[mt][j] = (f32x4){0.f, 0.f, 0.f, 0.f};

    for (int ch = 0; ch < 8; ++ch) {
        const int n0 = ns * 512 + ch * 64;
        __syncthreads();
        if (t < 128) {
            const int row = t >> 1, half = t & 1;
            uint4 kv = *(const uint4*)(Kh + (size_t)(n0 + row) * 16 + half * 8);
            const u16* ke = (const u16*)&kv;
#pragma unroll
            for (int e = 0; e < 8; ++e) {
                const float f = bf2f(ke[e]);
                kS[row][half * 8 + e] = f;
                kT[row][half * 8 + e] = f * 0.17677669529663687f;
            }
        } else if (t < 192) {
            const int row = t - 128;
            kS[row][16] = 1.f;  kS[row][17] = 1.f;  kS[row][18] = 0.f;
            kT[row][16] = 0.5f; kT[row][17] = 1.f;  kT[row][18] = 0.f;
        }
        // stage V^T from vt: conflict-free b128
#pragma unroll
        for (int i = 0; i < 2; ++i) {
            const int lin = i * 256 + t;
            const int f = lin >> 3, seg = lin & 7;
            *(uint4*)&Vs[f][seg * 8] =
                *(const uint4*)(Vth + (size_t)f * 2048 + n0 + seg * 8);
        }
        __syncthreads();
        {
            unsigned int* dst = (unsigned int*)&KFs[t][0];
#pragma unroll 8
            for (int i = 0; i < 32; ++i) {
                const float v0 = kS[2 * i][i2a]     * kT[2 * i][j2a];
                const float v1 = kS[2 * i + 1][i2a] * kT[2 * i + 1][j2a];
                dst[i] = (unsigned int)f2bf(v0) | ((unsigned int)f2bf(v1) << 16);
            }
            if (t < 32) {
                unsigned int* dst2 = (unsigned int*)&KFs[256 + t][0];
#pragma unroll 8
                for (int i = 0; i < 32; ++i) {
                    const float v0 = kS[2 * i][i2b]     * kT[2 * i][j2b];
                    const float v1 = kS[2 * i + 1][i2b] * kT[2 * i + 1][j2b];
                    dst2[i] = (unsigned int)f2bf(v0) | ((unsigned int)f2bf(v1) << 16);
                }
            }
        }
        __syncthreads();
#pragma unroll
        for (int kt = 0; kt < 2; ++kt) {
            s16x8 va[4];
#pragma unroll
            for (int mt = 0; mt < 4; ++mt)
                va[mt] = *(const s16x8*)&Vs[mt * 16 + c][kt * 32 + qd * 8];
#pragma unroll
            for (int j = 0; j < 5; ++j) {
                const int dt = w + 4 * j;
                if (dt < 18) {
                    s16x8 vb = *(const s16x8*)&KFs[dt * 16 + c][kt * 32 + qd * 8];
#pragma unroll
                    for (int mt = 0; mt < 4; ++mt)
                        acc[mt][j] = __builtin_amdgcn_mfma_f32_16x16x32_bf16(va[mt], vb, acc[mt][j], 0, 0, 0);
                }
            }
        }
    }

    float* base = kvpart + ((size_t)(ns * 64 + bh) * 64) * 273;
#pragma unroll
    for (int j = 0; j < 5; ++j) {
        const int dt = w + 4 * j;
        if (dt >= 18) continue;
        const int dd = dt * 16 + c;
        if (dd >= 273) continue;
#pragma unroll
        for (int mt = 0; mt < 4; ++mt)
#pragma unroll
            for (int r = 0; r < 4; ++r) {
                const int f = mt * 16 + qd * 4 + r;
                base[f * 273 + dd] = acc[mt][j][r];
            }
    }
}

// ---------------------------------------------------------------------------
extern "C" void kernel_launch(void* const* d_in, const int* in_sizes, int n_in,
                              void* d_out, int out_size, void* d_ws, size_t ws_size,
                              hipStream_t stream)
{
    const void* H  = d_in[0];
    const void* Wq = d_in[1];
    const void* Wk = d_in[2];
    const void* Wv = d_in[3];
    const void* Wo = d_in[4];
    const void* gw = d_in[5];
    float* outf = (float*)d_out;

    char* ws = (char*)d_ws;
    const size_t M = 1 << 20;
    u16*   Hb    = (u16*)(ws);                          // 16 MiB (reused as yn)
    u16*   Wqb   = (u16*)(ws + 16 * M);
    u16*   Wkb   = (u16*)(ws + 16 * M + 512 * 1024);
    u16*   Wvb   = (u16*)(ws + 17 * M);
    u16*   Wob   = (u16*)(ws + 19 * M);
    u16*   gwb   = (u16*)(ws + 21 * M);
    u16*   q     = (u16*)(ws + 22 * M);                 // 4 MiB
    u16*   k     = (u16*)(ws + 26 * M);                 // 4 MiB
    u16*   vt    = (u16*)(ws + 30 * M);                 // 16 MiB [b,h,64,l]
    float* kvpart= (float*)(ws + 46 * M);               // 4 x 4.27 MiB slabs
    u16*   yn    = Hb;                                  // reuse after gemm0

    cvt_all_kernel<<<2048, 256, 0, stream>>>(H, Wq, Wk, Wv, Wo, gw,
                                             Hb, Wqb, Wkb, Wvb, Wob, gwb);

    gemm_nt<0><<<dim3(12, 64), 256, 0, stream>>>(Hb, Wqb, Wkb, Wvb, q, k, vt,
                                                 nullptr, nullptr, nullptr);
    attn_kernel<<<dim3(4, 64), 512, 0, stream>>>(q, k, vt, gwb, yn);
    kv_mfma_kernel<<<dim3(4, 64), 256, 0, stream>>>(k, vt, kvpart);
    gemm_nt<1><<<dim3(8, 64), 256, 0, stream>>>(yn, Wob, nullptr, nullptr,
                                                nullptr, nullptr, nullptr, outf,
                                                kvpart, outf + (size_t)8388608);
}

// Round 10
// 218.703 us; speedup vs baseline: 1.1025x; 1.0429x over previous
//
#include <hip/hip_runtime.h>

// ---------------------------------------------------------------------------
// LinearAttention (Taylor feature map), MI355X/gfx950.
// Inputs: FLOAT32 (runtime-probed; bf16 copies in ws). Outputs: FLOAT32
// [out (4,2048,1024) | kv_state (4,16,1,64,273)].
//
// r16: kv_mfma rebuilt — KF features computed IN-REGISTER at MFMA time
// (lane (c,qd) of slot dt builds its B-fragment straight from kS via
// 2 b32 reads + mul + cvt_pk; deletes the 41KB KFs buffer, its build
// barrier, and the LDS write+read round-trip; 2 barriers/chunk, 14KB LDS)
// and split 8-way (grid (8,64) = 512 blocks = 2 blocks/CU = 8 waves/CU;
// was 1 block/CU = 4 waves, zero TLP, MfmaUtil 3.8%). kvpart = 8 slabs,
// summed in gemm1's epilogue. Everything else unchanged from r15.
// ---------------------------------------------------------------------------

typedef unsigned short u16;
typedef unsigned int u32;
typedef __attribute__((ext_vector_type(4))) float f32x4;
typedef __attribute__((ext_vector_type(16))) float f32x16;
typedef __attribute__((ext_vector_type(8))) short s16x8;

struct MaskT { static constexpr bool value = true;  };
struct MaskF { static constexpr bool value = false; };

__device__ __forceinline__ float bf2f(u16 u) {
    union { unsigned int i; float f; } x; x.i = ((unsigned int)u) << 16; return x.f;
}
__device__ __forceinline__ u16 f2bf(float f) {
    union { float f; unsigned int u; } x; x.f = f;
    unsigned int r = x.u + 0x7FFFu + ((x.u >> 16) & 1u);
    return (u16)(r >> 16);
}

typedef const __attribute__((address_space(1))) u32* gas1_t;
typedef __attribute__((address_space(3))) u32* las3_t;
__device__ __forceinline__ void gld16(const u16* g, u16* l) {
    __builtin_amdgcn_global_load_lds((gas1_t)(const void*)g, (las3_t)(void*)l, 16, 0, 0);
}

// ---------------- fused dtype probe + convert (one dispatch) ----------------
__global__ __launch_bounds__(256)
void cvt_all_kernel(const void* __restrict__ H,  const void* __restrict__ Wq,
                    const void* __restrict__ Wk, const void* __restrict__ Wv,
                    const void* __restrict__ Wo, const void* __restrict__ gw,
                    u16* __restrict__ Hb,  u16* __restrict__ Wqb,
                    u16* __restrict__ Wkb, u16* __restrict__ Wvb,
                    u16* __restrict__ Wob, u16* __restrict__ gwb)
{
    __shared__ int sflag;
    const int t = threadIdx.x;
    if (t < 64) {
        const unsigned int* Hw = (const unsigned int*)H;
        int cnt = 0;
#pragma unroll
        for (int i = 0; i < 16; ++i) {
            const unsigned int wrd = Hw[t * 16 + i];
            const int e = (int)((wrd >> 7) & 0xFFu);
            if (e >= 85 && e <= 170) ++cnt;
        }
        cnt += __shfl_xor(cnt, 1);  cnt += __shfl_xor(cnt, 2);
        cnt += __shfl_xor(cnt, 4);  cnt += __shfl_xor(cnt, 8);
        cnt += __shfl_xor(cnt, 16); cnt += __shfl_xor(cnt, 32);
        if (t == 0) sflag = (cnt < 700) ? 1 : 0;   // 1 = inputs are f32
    }
    __syncthreads();
    const int f32in = sflag;

    const int NQ = 11010112 / 4;                 // total quads
    for (int qi = blockIdx.x * 256 + t; qi < NQ; qi += gridDim.x * 256) {
        const int i = qi * 4;
        const void* src; u16* dst; int off;
        if      (i <  8388608) { src = H;  dst = Hb;  off = i; }
        else if (i <  8650752) { src = Wq; dst = Wqb; off = i - 8388608; }
        else if (i <  8912896) { src = Wk; dst = Wkb; off = i - 8650752; }
        else if (i <  9961472) { src = Wv; dst = Wvb; off = i - 8912896; }
        else if (i < 11010048) { src = Wo; dst = Wob; off = i - 9961472; }
        else                   { src = gw; dst = gwb; off = i - 11010048; }
        ushort4 o;
        if (f32in) {
            const float4 v = *((const float4*)src + (off >> 2));
            o.x = f2bf(v.x); o.y = f2bf(v.y); o.z = f2bf(v.z); o.w = f2bf(v.w);
        } else {
            o = *((const ushort4*)src + (off >> 2));
        }
        *(ushort4*)(dst + off) = o;
    }
}

// ---------------- GEMM: C = A(8192,1024) . B(N,1024)^T, bf16 in, f32 acc ----
// BK=64, 16 K-steps, 2 barriers each, both-sides XOR swizzle, chunked XCD
// swizzle. MODE 0: fused QKV; MODE 1: f32 out + 8-slab kv_fin epilogue.
template<int MODE>
__global__ __launch_bounds__(256)
void gemm_nt(const u16* __restrict__ A,
             const u16* __restrict__ Bq, const u16* __restrict__ Bk,
             const u16* __restrict__ Bv,
             u16* __restrict__ Oq, u16* __restrict__ Ok,
             u16* __restrict__ Ovt, float* __restrict__ Of,
             const float* __restrict__ Kvp, float* __restrict__ Kvo)
{
    __shared__ __attribute__((aligned(16))) u16 As[8192];   // 128 x 64
    __shared__ __attribute__((aligned(16))) u16 Bs[8192];
    const int t = threadIdx.x;
    const int lane = t & 63, w = t >> 6;
    const int c = lane & 15, qd = lane >> 4;
    const int wm = (w >> 1) * 64, wn = (w & 1) * 64;
    // chunked XCD swizzle: XCD x gets contiguous lid chunk (L2-fit panels)
    const int nwgx = gridDim.x;
    const int pid = blockIdx.y * nwgx + blockIdx.x;
    const int lid = (pid & 7) * ((nwgx * 64) >> 3) + (pid >> 3);
    const int rm = (lid / nwgx) * 128;
    const int cb = (lid % nwgx) * 128;

    const u16* Bsrc; int wrow0;
    if (MODE == 0) {
        if (cb < 256)      { Bsrc = Bq; wrow0 = cb; }
        else if (cb < 512) { Bsrc = Bk; wrow0 = cb - 256; }
        else               { Bsrc = Bv; wrow0 = cb - 512; }
    } else { Bsrc = Bq; wrow0 = cb; }

    f32x4 acc[4][4];
#pragma unroll
    for (int i = 0; i < 4; ++i)
#pragma unroll
        for (int j = 0; j < 4; ++j) acc[i][j] = (f32x4){0.f, 0.f, 0.f, 0.f};

    // staging: 4 issues per matrix per K-step; issue i covers rows [i*32,i*32+32)
    const int r0 = w * 8 + (lane >> 3);
    const int s0 = (lane & 7) ^ (lane >> 3);        // row&7 == lane>>3 here
    const u16* Ag = A    + (size_t)(rm    + r0) * 1024 + s0 * 8;
    const u16* Bg = Bsrc + (size_t)(wrow0 + r0) * 1024 + s0 * 8;
    u16* AsW = As + w * 512;    // wave-uniform LDS base (lane*16B added by HW)
    u16* BsW = Bs + w * 512;

    for (int kt = 0; kt < 16; ++kt) {
        const int k0 = kt * 64;
        __syncthreads();                        // prior readers done
#pragma unroll
        for (int i = 0; i < 4; ++i) {
            gld16(Ag + (size_t)(i * 32) * 1024 + k0, AsW + i * 2048);
            gld16(Bg + (size_t)(i * 32) * 1024 + k0, BsW + i * 2048);
        }
        __syncthreads();                        // drains vmcnt, joins waves
        s16x8 af[2][4], bfr[2][4];
#pragma unroll
        for (int kk = 0; kk < 2; ++kk) {
#pragma unroll
            for (int mt = 0; mt < 4; ++mt) {
                const int row = wm + mt * 16 + c;
                af[kk][mt] = *(const s16x8*)&As[row * 64 + (((kk * 4 + qd) ^ (row & 7)) * 8)];
            }
#pragma unroll
            for (int nt = 0; nt < 4; ++nt) {
                const int row = wn + nt * 16 + c;
                bfr[kk][nt] = *(const s16x8*)&Bs[row * 64 + (((kk * 4 + qd) ^ (row & 7)) * 8)];
            }
        }
#pragma unroll
        for (int kk = 0; kk < 2; ++kk)
#pragma unroll
            for (int mt = 0; mt < 4; ++mt)
#pragma unroll
                for (int nt = 0; nt < 4; ++nt)
                    acc[mt][nt] = __builtin_amdgcn_mfma_f32_16x16x32_bf16(af[kk][mt], bfr[kk][nt], acc[mt][nt], 0, 0, 0);
    }

#pragma unroll
    for (int mt = 0; mt < 4; ++mt) {
#pragma unroll
        for (int nt = 0; nt < 4; ++nt) {
            const int gc = cb + wn + nt * 16 + c;
            const int row0 = rm + wm + mt * 16 + qd * 4;
            if (MODE == 1) {
#pragma unroll
                for (int r = 0; r < 4; ++r)
                    Of[(size_t)(row0 + r) * 1024 + gc] = acc[mt][nt][r];
            } else if (gc < 512) {
#pragma unroll
                for (int r = 0; r < 4; ++r) {
                    const int row = row0 + r;
                    const int b_ = row >> 11, l_ = row & 2047;
                    const int cc = gc & 255;
                    const int h = cc >> 4, idx = cc & 15;
                    u16* dst = (gc < 256) ? Oq : Ok;
                    dst[(size_t)((b_ * 16 + h) * 2048 + l_) * 16 + idx] = f2bf(acc[mt][nt][r]);
                }
            } else {
                // V -> vt [b,h,64,l], r-consecutive => packed b64 store
                const int cc = gc - 512;
                const int h = cc >> 6, idx = cc & 63;
                const int b_ = row0 >> 11, l0 = row0 & 2047;
                ushort4 pk;
                pk.x = f2bf(acc[mt][nt][0]);
                pk.y = f2bf(acc[mt][nt][1]);
                pk.z = f2bf(acc[mt][nt][2]);
                pk.w = f2bf(acc[mt][nt][3]);
                *(ushort4*)(Ovt + ((size_t)((b_ * 16 + h) * 64 + idx)) * 2048 + l0) = pk;
            }
        }
    }

    // ---- grid-strided kv_fin epilogue (MODE 1 only): sum 8 slabs ----
    if (MODE == 1) {
        const int S = 64 * 64 * 273;             // floats per slab
        const int NQ4 = S / 4;
        const int NT = gridDim.x * gridDim.y * 256;
        for (int q = pid * 256 + t; q < NQ4; q += NT) {
            float4 a = ((const float4*)Kvp)[q];
#pragma unroll
            for (int s = 1; s < 8; ++s) {
                const float4 b = ((const float4*)(Kvp + (size_t)s * S))[q];
                a.x += b.x; a.y += b.y; a.z += b.z; a.w += b.w;
            }
            ((float4*)Kvo)[q] = a;
        }
    }
}

// ---------------- causal phi-attention + fused RMSNorm ----------------------
// 512 thr = 8 waves; block tile = 256 queries (wave w: 32 q). Pair (7-j, j)
// -> 18 chunks/block, perfectly balanced; grid (4,64) = 256 blocks.
__global__ __launch_bounds__(512, 2)
void attn_kernel(const u16* __restrict__ Qg, const u16* __restrict__ Kg,
                 const u16* __restrict__ Vt, const u16* __restrict__ gwb,
                 u16* __restrict__ Yn)
{
    __shared__ __attribute__((aligned(16))) u16 Vs[2][8192];   // 2 x 16 KB
    const int t = threadIdx.x, lane = t & 63, w = t >> 6;
    const int la = lane & 31, h = lane >> 5;
    // XCD swizzle: 256 blocks, 8 XCDs -> XCD x serves bh [8x, 8x+8)
    const int pid = blockIdx.y * 4 + blockIdx.x;
    const int lid = (pid & 7) * 32 + (pid >> 3);
    const int bh = lid >> 2;
    const int jj = lid & 3;                      // pair index 0..3
    const int b_ = bh >> 4, hh = bh & 15;
    const u16* Qh = Qg + (size_t)bh * (2048 * 16);
    const u16* Kh = Kg + (size_t)bh * (2048 * 16);
    const u16* Vh = Vt + (size_t)bh * (64 * 2048);
    const float gl0 = bf2f(gwb[la]);
    const float gl1 = bf2f(gwb[32 + la]);
    const f32x16 z16 = {0.f,0.f,0.f,0.f,0.f,0.f,0.f,0.f,
                        0.f,0.f,0.f,0.f,0.f,0.f,0.f,0.f};
    const int vbase0 = (la << 8) | (h << 4);     // V-frag lds byte base (ft=0)
    const int vsw = (la & 15) << 4;              // 4-bit XOR swizzle

    auto stageV = [&](int n0s, int bufsel) {
#pragma unroll
        for (int i = 0; i < 2; ++i) {
            const int slot = i * 512 + t;
            const int fl = slot >> 4;
            const int seg = (slot & 15) ^ (fl & 15);  // pre-swizzled source
            gld16(Vh + (size_t)fl * 2048 + n0s + seg * 8,
                  (u16*)Vs[bufsel] + (size_t)(i * 512 + (w << 6)) * 8);
        }
    };

    for (int pass = 0; pass < 2; ++pass) {
        const int qb = pass ? jj : (7 - jj);     // 256-query tile index
        const int q0 = qb * 256 + w * 32;        // wave's first query
        const int kf = 2 * qb + (w >> 2);        // wave's partial (diag) chunk
        const int wp = w & 3;                    // masked tile within it
        const int nck = 2 * qb + 2;              // chunks 0..nck-1

        const s16x8 bq = *(const s16x8*)(Qh + (size_t)(q0 + la) * 16 + h * 8);
        f32x16 yt0 = z16, yt1 = z16;
        s16x8 ka[4];
        const char* vsc = (const char*)Vs[0];

        auto loadK = [&](s16x8* kk, int kcL) {
#pragma unroll
            for (int kt = 0; kt < 4; ++kt)
                kk[kt] = *(const s16x8*)(Kh + (size_t)(kcL * 128 + kt * 32 + la) * 16 + h * 8);
        };

        auto tile = [&](int kt, auto MASKED) {
            constexpr bool masked = decltype(MASKED)::value;
            f32x16 sv = __builtin_amdgcn_mfma_f32_32x32x16_bf16(ka[kt], bq, z16, 0, 0, 0);
            float p[16];
#pragma unroll
            for (int r = 0; r < 16; ++r) {
                const float s = sv[r];
                float pv = fmaf(s, fmaf(s, 0.03125f, 0.25f), 1.0f);
                if (masked) {
                    const int keyloc = (r & 3) + 8 * (r >> 2) + 4 * h;
                    if (keyloc > la) pv = 0.f;
                }
                p[r] = pv;
            }
#pragma unroll
            for (int ks = 0; ks < 2; ++ks) {
                u32 X0, X1, Y0, Y1;
                asm("v_cvt_pk_bf16_f32 %0, %1, %2" : "=v"(X0) : "v"(p[8*ks+0]), "v"(p[8*ks+1]));
                asm("v_cvt_pk_bf16_f32 %0, %1, %2" : "=v"(X1) : "v"(p[8*ks+2]), "v"(p[8*ks+3]));
                asm("v_cvt_pk_bf16_f32 %0, %1, %2" : "=v"(Y0) : "v"(p[8*ks+4]), "v"(p[8*ks+5]));
                asm("v_cvt_pk_bf16_f32 %0, %1, %2" : "=v"(Y1) : "v"(p[8*ks+6]), "v"(p[8*ks+7]));
                // exchange halves: after swap X holds W0 (lo keys), Y holds W2
                asm("v_permlane32_swap_b32 %0, %1" : "+v"(X0), "+v"(Y0));
                asm("v_permlane32_swap_b32 %0, %1" : "+v"(X1), "+v"(Y1));
                union { uint4 u; s16x8 v; } afu;
                afu.u = (uint4){X0, X1, Y0, Y1};
                const int offb = (kt << 6) | (ks << 5);
                const s16x8 vb0 = *(const s16x8*)(vsc + (((vbase0 + offb)) ^ vsw));
                const s16x8 vb1 = *(const s16x8*)(vsc + (((vbase0 + 8192 + offb)) ^ vsw));
                yt0 = __builtin_amdgcn_mfma_f32_32x32x16_bf16(afu.v, vb0, yt0, 0, 0, 0);
                yt1 = __builtin_amdgcn_mfma_f32_32x32x16_bf16(afu.v, vb1, yt1, 0, 0, 0);
            }
        };

        // prologue: stage chunk 0, preload K(0)
        stageV(0, 0);
        loadK(ka, 0);
        __syncthreads();                         // drains gld_lds

        for (int kc = 0; kc < nck; ++kc) {
            const int cur = kc & 1;
            vsc = (const char*)Vs[cur];
            if (kc + 1 < nck) stageV((kc + 1) * 128, cur ^ 1);
            s16x8 kn[4] = {ka[0], ka[1], ka[2], ka[3]};
            if (kc < kf) loadK(kn, kc + 1);      // prefetch next K frags

            if (kc < kf) {
                tile(0, MaskF{}); tile(1, MaskF{});
                tile(2, MaskF{}); tile(3, MaskF{});
            } else if (kc == kf) {
                if (wp == 0)      { tile(0, MaskT{}); }
                else if (wp == 1) { tile(0, MaskF{}); tile(1, MaskT{}); }
                else if (wp == 2) { tile(0, MaskF{}); tile(1, MaskF{}); tile(2, MaskT{}); }
                else              { tile(0, MaskF{}); tile(1, MaskF{}); tile(2, MaskF{}); tile(3, MaskT{}); }
            }
            __syncthreads();                     // drains vmcnt: next V staged
#pragma unroll
            for (int kt = 0; kt < 4; ++kt) ka[kt] = kn[kt];
        }

        // ---- fused RMSNorm + store yn [b,l,1024] ----
#pragma unroll
        for (int r = 0; r < 16; ++r) {
            float ss = yt0[r] * yt0[r] + yt1[r] * yt1[r];
            ss += __shfl_xor(ss, 1);  ss += __shfl_xor(ss, 2);
            ss += __shfl_xor(ss, 4);  ss += __shfl_xor(ss, 8);
            ss += __shfl_xor(ss, 16);
            const float rmsv = rsqrtf(ss * (1.0f / 64.0f) + 1e-5f);
            const int row = q0 + (r & 3) + 8 * (r >> 2) + 4 * h;
            u16* dst = Yn + ((size_t)(b_ * 2048 + row)) * 1024 + hh * 64;
            dst[la]      = f2bf(yt0[r] * rmsv * gl0);
            dst[32 + la] = f2bf(yt1[r] * rmsv * gl1);
        }
    }
}

// ---------------- kv_state as MFMA GEMM, KF in-register ---------------------
// grid (8,64) = 512 blocks (2/CU, 8 waves/CU), 4 chunks of 64 keys each.
// Per chunk: stage K (f32, stride-17 pad) + V^T -> 1 barrier -> MFMA with
// B-fragments (phi features) built in-register from kS: lane (c,qd) of slot
// dt needs feature dd=dt*16+c for keys qd*8+e: {1, 0.5*k, 0.1768*ki*kj}.
// No KFs buffer, no build barrier. 2 barriers/chunk, ~14 KB LDS.
__global__ __launch_bounds__(256)
void kv_mfma_kernel(const u16* __restrict__ Kg, const u16* __restrict__ Vt,
                    float* __restrict__ kvpart)
{
    __shared__ __attribute__((aligned(16))) float kS[64][17];
    __shared__ __attribute__((aligned(16))) u16 Vs[64][72];
    const int t = threadIdx.x, lane = t & 63, w = t >> 6;
    const int c = lane & 15, qd = lane >> 4;
    const int ns = blockIdx.x, bh = blockIdx.y;
    const u16* Kh  = Kg + (size_t)bh * 2048 * 16;
    const u16* Vth = Vt + (size_t)bh * 64 * 2048;

    f32x4 acc[4][5];
#pragma unroll
    for (int mt = 0; mt < 4; ++mt)
#pragma unroll
        for (int j = 0; j < 5; ++j) acc[mt][j] = (f32x4){0.f, 0.f, 0.f, 0.f};

    for (int ch = 0; ch < 4; ++ch) {
        const int n0 = ns * 256 + ch * 64;
        __syncthreads();                        // prior readers done
        if (t < 128) {                          // stage K chunk as f32
            const int row = t >> 1, half = t & 1;
            uint4 kv = *(const uint4*)(Kh + (size_t)(n0 + row) * 16 + half * 8);
            const u16* ke = (const u16*)&kv;
#pragma unroll
            for (int e = 0; e < 8; ++e)
                kS[row][half * 8 + e] = bf2f(ke[e]);
        }
#pragma unroll
        for (int i = 0; i < 2; ++i) {           // stage V^T chunk
            const int lin = i * 256 + t;
            const int f = lin >> 3, seg = lin & 7;
            *(uint4*)&Vs[f][seg * 8] =
                *(const uint4*)(Vth + (size_t)f * 2048 + n0 + seg * 8);
        }
        __syncthreads();

#pragma unroll
        for (int kt = 0; kt < 2; ++kt) {
            s16x8 va[4];
#pragma unroll
            for (int mt = 0; mt < 4; ++mt)
                va[mt] = *(const s16x8*)&Vs[mt * 16 + c][kt * 32 + qd * 8];
#pragma unroll
            for (int j = 0; j < 5; ++j) {
                const int dt = w + 4 * j;       // wave-uniform
                if (dt < 18) {
                    const int dd = dt * 16 + c;
                    const int i2 = (dd - 17) >> 4, j2 = (dd - 17) & 15;
                    const int nb = kt * 32 + qd * 8;
                    u32 vbw[4];
#pragma unroll
                    for (int p = 0; p < 4; ++p) {
                        float pv[2];
#pragma unroll
                        for (int h2 = 0; h2 < 2; ++h2) {
                            const int n = nb + 2 * p + h2;
                            float val;
                            if (dd == 0)       val = 1.0f;
                            else if (dd < 17)  val = 0.5f * kS[n][dd - 1];
                            else               val = 0.17677669529663687f
                                                     * kS[n][i2] * kS[n][j2];
                            pv[h2] = val;
                        }
                        asm("v_cvt_pk_bf16_f32 %0, %1, %2"
                            : "=v"(vbw[p]) : "v"(pv[0]), "v"(pv[1]));
                    }
                    union { uint4 u; s16x8 v; } vbu;
                    vbu.u = (uint4){vbw[0], vbw[1], vbw[2], vbw[3]};
#pragma unroll
                    for (int mt = 0; mt < 4; ++mt)
                        acc[mt][j] = __builtin_amdgcn_mfma_f32_16x16x32_bf16(
                            va[mt], vbu.v, acc[mt][j], 0, 0, 0);
                }
            }
        }
    }

    float* base = kvpart + ((size_t)(ns * 64 + bh) * 64) * 273;
#pragma unroll
    for (int j = 0; j < 5; ++j) {
        const int dt = w + 4 * j;
        if (dt >= 18) continue;
        const int dd = dt * 16 + c;
        if (dd >= 273) continue;
#pragma unroll
        for (int mt = 0; mt < 4; ++mt)
#pragma unroll
            for (int r = 0; r < 4; ++r) {
                const int f = mt * 16 + qd * 4 + r;
                base[f * 273 + dd] = acc[mt][j][r];
            }
    }
}

// ---------------------------------------------------------------------------
extern "C" void kernel_launch(void* const* d_in, const int* in_sizes, int n_in,
                              void* d_out, int out_size, void* d_ws, size_t ws_size,
                              hipStream_t stream)
{
    const void* H  = d_in[0];
    const void* Wq = d_in[1];
    const void* Wk = d_in[2];
    const void* Wv = d_in[3];
    const void* Wo = d_in[4];
    const void* gw = d_in[5];
    float* outf = (float*)d_out;

    char* ws = (char*)d_ws;
    const size_t M = 1 << 20;
    u16*   Hb    = (u16*)(ws);                          // 16 MiB (reused as yn)
    u16*   Wqb   = (u16*)(ws + 16 * M);
    u16*   Wkb   = (u16*)(ws + 16 * M + 512 * 1024);
    u16*   Wvb   = (u16*)(ws + 17 * M);
    u16*   Wob   = (u16*)(ws + 19 * M);
    u16*   gwb   = (u16*)(ws + 21 * M);
    u16*   q     = (u16*)(ws + 22 * M);                 // 4 MiB
    u16*   k     = (u16*)(ws + 26 * M);                 // 4 MiB
    u16*   vt    = (u16*)(ws + 30 * M);                 // 16 MiB [b,h,64,l]
    float* kvpart= (float*)(ws + 46 * M);               // 8 x 4.47 MiB slabs
    u16*   yn    = Hb;                                  // reuse after gemm0

    cvt_all_kernel<<<2048, 256, 0, stream>>>(H, Wq, Wk, Wv, Wo, gw,
                                             Hb, Wqb, Wkb, Wvb, Wob, gwb);

    gemm_nt<0><<<dim3(12, 64), 256, 0, stream>>>(Hb, Wqb, Wkb, Wvb, q, k, vt,
                                                 nullptr, nullptr, nullptr);
    attn_kernel<<<dim3(4, 64), 512, 0, stream>>>(q, k, vt, gwb, yn);
    kv_mfma_kernel<<<dim3(8, 64), 256, 0, stream>>>(k, vt, kvpart);
    gemm_nt<1><<<dim3(8, 64), 256, 0, stream>>>(yn, Wob, nullptr, nullptr,
                                                nullptr, nullptr, nullptr, outf,
                                                kvpart, outf + (size_t)8388608);
}

// Round 11
// 202.141 us; speedup vs baseline: 1.1929x; 1.0819x over previous
//
#include <hip/hip_runtime.h>

// ---------------------------------------------------------------------------
// LinearAttention (Taylor feature map), MI355X/gfx950.
// Inputs: FLOAT32 (runtime-probed; bf16 copies in ws). Outputs: FLOAT32
// [out (4,2048,1024) | kv_state (4,16,1,64,273)].
//
// r17: attn + kv_mfma merged into ONE heterogeneous 512-block dispatch
// (fixes r13's three defects: no dispatch-order/co-residency assumption —
// scheduler mixes freely; kv rebuilt for all 512 threads (8 waves,
// dt=w+8j); unified LDS only 32KB -> 2+ blocks/CU so attn and kv blocks
// co-schedule and fill each other's latency slots). kvpart back to 4
// slabs. Dispatches 5 -> 4. cvt_all / gemm_nt unchanged from r16.
// ---------------------------------------------------------------------------

typedef unsigned short u16;
typedef unsigned int u32;
typedef __attribute__((ext_vector_type(4))) float f32x4;
typedef __attribute__((ext_vector_type(16))) float f32x16;
typedef __attribute__((ext_vector_type(8))) short s16x8;

struct MaskT { static constexpr bool value = true;  };
struct MaskF { static constexpr bool value = false; };

__device__ __forceinline__ float bf2f(u16 u) {
    union { unsigned int i; float f; } x; x.i = ((unsigned int)u) << 16; return x.f;
}
__device__ __forceinline__ u16 f2bf(float f) {
    union { float f; unsigned int u; } x; x.f = f;
    unsigned int r = x.u + 0x7FFFu + ((x.u >> 16) & 1u);
    return (u16)(r >> 16);
}

typedef const __attribute__((address_space(1))) u32* gas1_t;
typedef __attribute__((address_space(3))) u32* las3_t;
__device__ __forceinline__ void gld16(const u16* g, u16* l) {
    __builtin_amdgcn_global_load_lds((gas1_t)(const void*)g, (las3_t)(void*)l, 16, 0, 0);
}

// ---------------- fused dtype probe + convert (one dispatch) ----------------
__global__ __launch_bounds__(256)
void cvt_all_kernel(const void* __restrict__ H,  const void* __restrict__ Wq,
                    const void* __restrict__ Wk, const void* __restrict__ Wv,
                    const void* __restrict__ Wo, const void* __restrict__ gw,
                    u16* __restrict__ Hb,  u16* __restrict__ Wqb,
                    u16* __restrict__ Wkb, u16* __restrict__ Wvb,
                    u16* __restrict__ Wob, u16* __restrict__ gwb)
{
    __shared__ int sflag;
    const int t = threadIdx.x;
    if (t < 64) {
        const unsigned int* Hw = (const unsigned int*)H;
        int cnt = 0;
#pragma unroll
        for (int i = 0; i < 16; ++i) {
            const unsigned int wrd = Hw[t * 16 + i];
            const int e = (int)((wrd >> 7) & 0xFFu);
            if (e >= 85 && e <= 170) ++cnt;
        }
        cnt += __shfl_xor(cnt, 1);  cnt += __shfl_xor(cnt, 2);
        cnt += __shfl_xor(cnt, 4);  cnt += __shfl_xor(cnt, 8);
        cnt += __shfl_xor(cnt, 16); cnt += __shfl_xor(cnt, 32);
        if (t == 0) sflag = (cnt < 700) ? 1 : 0;   // 1 = inputs are f32
    }
    __syncthreads();
    const int f32in = sflag;

    const int NQ = 11010112 / 4;                 // total quads
    for (int qi = blockIdx.x * 256 + t; qi < NQ; qi += gridDim.x * 256) {
        const int i = qi * 4;
        const void* src; u16* dst; int off;
        if      (i <  8388608) { src = H;  dst = Hb;  off = i; }
        else if (i <  8650752) { src = Wq; dst = Wqb; off = i - 8388608; }
        else if (i <  8912896) { src = Wk; dst = Wkb; off = i - 8650752; }
        else if (i <  9961472) { src = Wv; dst = Wvb; off = i - 8912896; }
        else if (i < 11010048) { src = Wo; dst = Wob; off = i - 9961472; }
        else                   { src = gw; dst = gwb; off = i - 11010048; }
        ushort4 o;
        if (f32in) {
            const float4 v = *((const float4*)src + (off >> 2));
            o.x = f2bf(v.x); o.y = f2bf(v.y); o.z = f2bf(v.z); o.w = f2bf(v.w);
        } else {
            o = *((const ushort4*)src + (off >> 2));
        }
        *(ushort4*)(dst + off) = o;
    }
}

// ---------------- GEMM: C = A(8192,1024) . B(N,1024)^T, bf16 in, f32 acc ----
// BK=64, 16 K-steps, 2 barriers each, both-sides XOR swizzle, chunked XCD
// swizzle. MODE 0: fused QKV; MODE 1: f32 out + 4-slab kv_fin epilogue.
template<int MODE>
__global__ __launch_bounds__(256)
void gemm_nt(const u16* __restrict__ A,
             const u16* __restrict__ Bq, const u16* __restrict__ Bk,
             const u16* __restrict__ Bv,
             u16* __restrict__ Oq, u16* __restrict__ Ok,
             u16* __restrict__ Ovt, float* __restrict__ Of,
             const float* __restrict__ Kvp, float* __restrict__ Kvo)
{
    __shared__ __attribute__((aligned(16))) u16 As[8192];   // 128 x 64
    __shared__ __attribute__((aligned(16))) u16 Bs[8192];
    const int t = threadIdx.x;
    const int lane = t & 63, w = t >> 6;
    const int c = lane & 15, qd = lane >> 4;
    const int wm = (w >> 1) * 64, wn = (w & 1) * 64;
    // chunked XCD swizzle: XCD x gets contiguous lid chunk (L2-fit panels)
    const int nwgx = gridDim.x;
    const int pid = blockIdx.y * nwgx + blockIdx.x;
    const int lid = (pid & 7) * ((nwgx * 64) >> 3) + (pid >> 3);
    const int rm = (lid / nwgx) * 128;
    const int cb = (lid % nwgx) * 128;

    const u16* Bsrc; int wrow0;
    if (MODE == 0) {
        if (cb < 256)      { Bsrc = Bq; wrow0 = cb; }
        else if (cb < 512) { Bsrc = Bk; wrow0 = cb - 256; }
        else               { Bsrc = Bv; wrow0 = cb - 512; }
    } else { Bsrc = Bq; wrow0 = cb; }

    f32x4 acc[4][4];
#pragma unroll
    for (int i = 0; i < 4; ++i)
#pragma unroll
        for (int j = 0; j < 4; ++j) acc[i][j] = (f32x4){0.f, 0.f, 0.f, 0.f};

    // staging: 4 issues per matrix per K-step; issue i covers rows [i*32,i*32+32)
    const int r0 = w * 8 + (lane >> 3);
    const int s0 = (lane & 7) ^ (lane >> 3);        // row&7 == lane>>3 here
    const u16* Ag = A    + (size_t)(rm    + r0) * 1024 + s0 * 8;
    const u16* Bg = Bsrc + (size_t)(wrow0 + r0) * 1024 + s0 * 8;
    u16* AsW = As + w * 512;    // wave-uniform LDS base (lane*16B added by HW)
    u16* BsW = Bs + w * 512;

    for (int kt = 0; kt < 16; ++kt) {
        const int k0 = kt * 64;
        __syncthreads();                        // prior readers done
#pragma unroll
        for (int i = 0; i < 4; ++i) {
            gld16(Ag + (size_t)(i * 32) * 1024 + k0, AsW + i * 2048);
            gld16(Bg + (size_t)(i * 32) * 1024 + k0, BsW + i * 2048);
        }
        __syncthreads();                        // drains vmcnt, joins waves
        s16x8 af[2][4], bfr[2][4];
#pragma unroll
        for (int kk = 0; kk < 2; ++kk) {
#pragma unroll
            for (int mt = 0; mt < 4; ++mt) {
                const int row = wm + mt * 16 + c;
                af[kk][mt] = *(const s16x8*)&As[row * 64 + (((kk * 4 + qd) ^ (row & 7)) * 8)];
            }
#pragma unroll
            for (int nt = 0; nt < 4; ++nt) {
                const int row = wn + nt * 16 + c;
                bfr[kk][nt] = *(const s16x8*)&Bs[row * 64 + (((kk * 4 + qd) ^ (row & 7)) * 8)];
            }
        }
#pragma unroll
        for (int kk = 0; kk < 2; ++kk)
#pragma unroll
            for (int mt = 0; mt < 4; ++mt)
#pragma unroll
                for (int nt = 0; nt < 4; ++nt)
                    acc[mt][nt] = __builtin_amdgcn_mfma_f32_16x16x32_bf16(af[kk][mt], bfr[kk][nt], acc[mt][nt], 0, 0, 0);
    }

#pragma unroll
    for (int mt = 0; mt < 4; ++mt) {
#pragma unroll
        for (int nt = 0; nt < 4; ++nt) {
            const int gc = cb + wn + nt * 16 + c;
            const int row0 = rm + wm + mt * 16 + qd * 4;
            if (MODE == 1) {
#pragma unroll
                for (int r = 0; r < 4; ++r)
                    Of[(size_t)(row0 + r) * 1024 + gc] = acc[mt][nt][r];
            } else if (gc < 512) {
#pragma unroll
                for (int r = 0; r < 4; ++r) {
                    const int row = row0 + r;
                    const int b_ = row >> 11, l_ = row & 2047;
                    const int cc = gc & 255;
                    const int h = cc >> 4, idx = cc & 15;
                    u16* dst = (gc < 256) ? Oq : Ok;
                    dst[(size_t)((b_ * 16 + h) * 2048 + l_) * 16 + idx] = f2bf(acc[mt][nt][r]);
                }
            } else {
                // V -> vt [b,h,64,l], r-consecutive => packed b64 store
                const int cc = gc - 512;
                const int h = cc >> 6, idx = cc & 63;
                const int b_ = row0 >> 11, l0 = row0 & 2047;
                ushort4 pk;
                pk.x = f2bf(acc[mt][nt][0]);
                pk.y = f2bf(acc[mt][nt][1]);
                pk.z = f2bf(acc[mt][nt][2]);
                pk.w = f2bf(acc[mt][nt][3]);
                *(ushort4*)(Ovt + ((size_t)((b_ * 16 + h) * 64 + idx)) * 2048 + l0) = pk;
            }
        }
    }

    // ---- grid-strided kv_fin epilogue (MODE 1 only): sum 4 slabs ----
    if (MODE == 1) {
        const int S = 64 * 64 * 273;             // floats per slab
        const int NQ4 = S / 4;
        const int NT = gridDim.x * gridDim.y * 256;
        for (int q = pid * 256 + t; q < NQ4; q += NT) {
            float4 a = ((const float4*)Kvp)[q];
#pragma unroll
            for (int s = 1; s < 4; ++s) {
                const float4 b = ((const float4*)(Kvp + (size_t)s * S))[q];
                a.x += b.x; a.y += b.y; a.z += b.z; a.w += b.w;
            }
            ((float4*)Kvo)[q] = a;
        }
    }
}

// ---------------- merged attn + kv_state (heterogeneous grid) ---------------
// grid (8,64) = 512 blocks x 512 thr, LDS 32KB -> 2+ blocks/CU, scheduler
// mixes block types freely. pid = y*8+x: xcd = pid&7, idx = pid>>3.
// idx<32: attn task-pair block (r15 structure). idx>=32: kv block with all
// 8 waves active (dt = w+8j, j<3; bh = xcd*8+(c2>>2), ns = c2&3, 8 chunks).
__global__ __launch_bounds__(512, 4)
void akv_kernel(const u16* __restrict__ Qg, const u16* __restrict__ Kg,
                const u16* __restrict__ Vt, const u16* __restrict__ gwb,
                u16* __restrict__ Yn, float* __restrict__ kvpart)
{
    __shared__ __attribute__((aligned(16))) char lds[32768];
    const int t = threadIdx.x, lane = t & 63, w = t >> 6;
    const int pid = blockIdx.y * 8 + blockIdx.x;
    const int x = pid & 7;                       // XCD
    const int idx = pid >> 3;                    // 0..63

    if (idx < 32) {
        // ===================== attn body (r15 structure) ====================
        const int la = lane & 31, h = lane >> 5;
        const int lid = x * 32 + idx;
        const int bh = lid >> 2;
        const int jj = lid & 3;                  // pair index 0..3
        const int b_ = bh >> 4, hh = bh & 15;
        const u16* Qh = Qg + (size_t)bh * (2048 * 16);
        const u16* Kh = Kg + (size_t)bh * (2048 * 16);
        const u16* Vh = Vt + (size_t)bh * (64 * 2048);
        const float gl0 = bf2f(gwb[la]);
        const float gl1 = bf2f(gwb[32 + la]);
        const f32x16 z16 = {0.f,0.f,0.f,0.f,0.f,0.f,0.f,0.f,
                            0.f,0.f,0.f,0.f,0.f,0.f,0.f,0.f};
        const int vbase0 = (la << 8) | (h << 4);
        const int vsw = (la & 15) << 4;          // 4-bit XOR swizzle
        u16* VsB = (u16*)lds;                    // 2 x 8192 u16

        auto stageV = [&](int n0s, int bufsel) {
#pragma unroll
            for (int i = 0; i < 2; ++i) {
                const int slot = i * 512 + t;
                const int fl = slot >> 4;
                const int seg = (slot & 15) ^ (fl & 15);  // pre-swizzled source
                gld16(Vh + (size_t)fl * 2048 + n0s + seg * 8,
                      VsB + (size_t)bufsel * 8192 + (size_t)(i * 512 + (w << 6)) * 8);
            }
        };

        for (int pass = 0; pass < 2; ++pass) {
            const int qb = pass ? jj : (7 - jj);
            const int q0 = qb * 256 + w * 32;
            const int kf = 2 * qb + (w >> 2);
            const int wp = w & 3;
            const int nck = 2 * qb + 2;

            const s16x8 bq = *(const s16x8*)(Qh + (size_t)(q0 + la) * 16 + h * 8);
            f32x16 yt0 = z16, yt1 = z16;
            s16x8 ka[4];
            const char* vsc = (const char*)VsB;

            auto loadK = [&](s16x8* kk, int kcL) {
#pragma unroll
                for (int kt = 0; kt < 4; ++kt)
                    kk[kt] = *(const s16x8*)(Kh + (size_t)(kcL * 128 + kt * 32 + la) * 16 + h * 8);
            };

            auto tile = [&](int kt, auto MASKED) {
                constexpr bool masked = decltype(MASKED)::value;
                f32x16 sv = __builtin_amdgcn_mfma_f32_32x32x16_bf16(ka[kt], bq, z16, 0, 0, 0);
                float p[16];
#pragma unroll
                for (int r = 0; r < 16; ++r) {
                    const float s = sv[r];
                    float pv = fmaf(s, fmaf(s, 0.03125f, 0.25f), 1.0f);
                    if (masked) {
                        const int keyloc = (r & 3) + 8 * (r >> 2) + 4 * h;
                        if (keyloc > la) pv = 0.f;
                    }
                    p[r] = pv;
                }
#pragma unroll
                for (int ks = 0; ks < 2; ++ks) {
                    u32 X0, X1, Y0, Y1;
                    asm("v_cvt_pk_bf16_f32 %0, %1, %2" : "=v"(X0) : "v"(p[8*ks+0]), "v"(p[8*ks+1]));
                    asm("v_cvt_pk_bf16_f32 %0, %1, %2" : "=v"(X1) : "v"(p[8*ks+2]), "v"(p[8*ks+3]));
                    asm("v_cvt_pk_bf16_f32 %0, %1, %2" : "=v"(Y0) : "v"(p[8*ks+4]), "v"(p[8*ks+5]));
                    asm("v_cvt_pk_bf16_f32 %0, %1, %2" : "=v"(Y1) : "v"(p[8*ks+6]), "v"(p[8*ks+7]));
                    asm("v_permlane32_swap_b32 %0, %1" : "+v"(X0), "+v"(Y0));
                    asm("v_permlane32_swap_b32 %0, %1" : "+v"(X1), "+v"(Y1));
                    union { uint4 u; s16x8 v; } afu;
                    afu.u = (uint4){X0, X1, Y0, Y1};
                    const int offb = (kt << 6) | (ks << 5);
                    const s16x8 vb0 = *(const s16x8*)(vsc + (((vbase0 + offb)) ^ vsw));
                    const s16x8 vb1 = *(const s16x8*)(vsc + (((vbase0 + 8192 + offb)) ^ vsw));
                    yt0 = __builtin_amdgcn_mfma_f32_32x32x16_bf16(afu.v, vb0, yt0, 0, 0, 0);
                    yt1 = __builtin_amdgcn_mfma_f32_32x32x16_bf16(afu.v, vb1, yt1, 0, 0, 0);
                }
            };

            stageV(0, 0);
            loadK(ka, 0);
            __syncthreads();

            for (int kc = 0; kc < nck; ++kc) {
                const int cur = kc & 1;
                vsc = (const char*)(VsB + (size_t)cur * 8192);
                if (kc + 1 < nck) stageV((kc + 1) * 128, cur ^ 1);
                s16x8 kn[4] = {ka[0], ka[1], ka[2], ka[3]};
                if (kc < kf) loadK(kn, kc + 1);

                if (kc < kf) {
                    tile(0, MaskF{}); tile(1, MaskF{});
                    tile(2, MaskF{}); tile(3, MaskF{});
                } else if (kc == kf) {
                    if (wp == 0)      { tile(0, MaskT{}); }
                    else if (wp == 1) { tile(0, MaskF{}); tile(1, MaskT{}); }
                    else if (wp == 2) { tile(0, MaskF{}); tile(1, MaskF{}); tile(2, MaskT{}); }
                    else              { tile(0, MaskF{}); tile(1, MaskF{}); tile(2, MaskF{}); tile(3, MaskT{}); }
                }
                __syncthreads();
#pragma unroll
                for (int kt = 0; kt < 4; ++kt) ka[kt] = kn[kt];
            }

#pragma unroll
            for (int r = 0; r < 16; ++r) {
                float ss = yt0[r] * yt0[r] + yt1[r] * yt1[r];
                ss += __shfl_xor(ss, 1);  ss += __shfl_xor(ss, 2);
                ss += __shfl_xor(ss, 4);  ss += __shfl_xor(ss, 8);
                ss += __shfl_xor(ss, 16);
                const float rmsv = rsqrtf(ss * (1.0f / 64.0f) + 1e-5f);
                const int row = q0 + (r & 3) + 8 * (r >> 2) + 4 * h;
                u16* dst = Yn + ((size_t)(b_ * 2048 + row)) * 1024 + hh * 64;
                dst[la]      = f2bf(yt0[r] * rmsv * gl0);
                dst[32 + la] = f2bf(yt1[r] * rmsv * gl1);
            }
        }
    } else {
        // ============== kv body: all 8 waves active, dt = w + 8j ============
        const int c2 = idx - 32;                 // 0..31
        const int bh = x * 8 + (c2 >> 2);
        const int ns = c2 & 3;
        const int c = lane & 15, qd = lane >> 4;
        const u16* Kh  = Kg + (size_t)bh * 2048 * 16;
        const u16* Vth = Vt + (size_t)bh * 64 * 2048;
        float (*kS)[17] = (float(*)[17])lds;               // 4352 B
        u16 (*Vs)[72]   = (u16(*)[72])(lds + 4608);        // 9216 B

        f32x4 acc[4][3];
#pragma unroll
        for (int mt = 0; mt < 4; ++mt)
#pragma unroll
            for (int j = 0; j < 3; ++j) acc[mt][j] = (f32x4){0.f, 0.f, 0.f, 0.f};

        for (int ch = 0; ch < 8; ++ch) {
            const int n0 = ns * 512 + ch * 64;
            __syncthreads();                    // prior readers done
            if (t < 128) {                      // stage K chunk as f32
                const int row = t >> 1, half = t & 1;
                uint4 kv = *(const uint4*)(Kh + (size_t)(n0 + row) * 16 + half * 8);
                const u16* ke = (const u16*)&kv;
#pragma unroll
                for (int e = 0; e < 8; ++e)
                    kS[row][half * 8 + e] = bf2f(ke[e]);
            }
            {                                   // stage V^T: one b128/thread
                const int f = t >> 3, seg = t & 7;
                *(uint4*)&Vs[f][seg * 8] =
                    *(const uint4*)(Vth + (size_t)f * 2048 + n0 + seg * 8);
            }
            __syncthreads();

#pragma unroll
            for (int kt = 0; kt < 2; ++kt) {
                s16x8 va[4];
#pragma unroll
                for (int mt = 0; mt < 4; ++mt)
                    va[mt] = *(const s16x8*)&Vs[mt * 16 + c][kt * 32 + qd * 8];
#pragma unroll
                for (int j = 0; j < 3; ++j) {
                    const int dt = w + 8 * j;   // wave-uniform
                    if (dt < 18) {
                        const int dd = dt * 16 + c;
                        const int i2 = (dd - 17) >> 4, j2 = (dd - 17) & 15;
                        const int nb = kt * 32 + qd * 8;
                        u32 vbw[4];
#pragma unroll
                        for (int p = 0; p < 4; ++p) {
                            float pv[2];
#pragma unroll
                            for (int h2 = 0; h2 < 2; ++h2) {
                                const int n = nb + 2 * p + h2;
                                float val;
                                if (dd == 0)       val = 1.0f;
                                else if (dd < 17)  val = 0.5f * kS[n][dd - 1];
                                else               val = 0.17677669529663687f
                                                         * kS[n][i2] * kS[n][j2];
                                pv[h2] = val;
                            }
                            asm("v_cvt_pk_bf16_f32 %0, %1, %2"
                                : "=v"(vbw[p]) : "v"(pv[0]), "v"(pv[1]));
                        }
                        union { uint4 u; s16x8 v; } vbu;
                        vbu.u = (uint4){vbw[0], vbw[1], vbw[2], vbw[3]};
#pragma unroll
                        for (int mt = 0; mt < 4; ++mt)
                            acc[mt][j] = __builtin_amdgcn_mfma_f32_16x16x32_bf16(
                                va[mt], vbu.v, acc[mt][j], 0, 0, 0);
                    }
                }
            }
        }

        float* base = kvpart + ((size_t)(ns * 64 + bh) * 64) * 273;
#pragma unroll
        for (int j = 0; j < 3; ++j) {
            const int dt = w + 8 * j;
            if (dt >= 18) continue;
            const int dd = dt * 16 + c;
            if (dd >= 273) continue;
#pragma unroll
            for (int mt = 0; mt < 4; ++mt)
#pragma unroll
                for (int r = 0; r < 4; ++r) {
                    const int f = mt * 16 + qd * 4 + r;
                    base[f * 273 + dd] = acc[mt][j][r];
                }
        }
    }
}

// ---------------------------------------------------------------------------
extern "C" void kernel_launch(void* const* d_in, const int* in_sizes, int n_in,
                              void* d_out, int out_size, void* d_ws, size_t ws_size,
                              hipStream_t stream)
{
    const void* H  = d_in[0];
    const void* Wq = d_in[1];
    const void* Wk = d_in[2];
    const void* Wv = d_in[3];
    const void* Wo = d_in[4];
    const void* gw = d_in[5];
    float* outf = (float*)d_out;

    char* ws = (char*)d_ws;
    const size_t M = 1 << 20;
    u16*   Hb    = (u16*)(ws);                          // 16 MiB (reused as yn)
    u16*   Wqb   = (u16*)(ws + 16 * M);
    u16*   Wkb   = (u16*)(ws + 16 * M + 512 * 1024);
    u16*   Wvb   = (u16*)(ws + 17 * M);
    u16*   Wob   = (u16*)(ws + 19 * M);
    u16*   gwb   = (u16*)(ws + 21 * M);
    u16*   q     = (u16*)(ws + 22 * M);                 // 4 MiB
    u16*   k     = (u16*)(ws + 26 * M);                 // 4 MiB
    u16*   vt    = (u16*)(ws + 30 * M);                 // 16 MiB [b,h,64,l]
    float* kvpart= (float*)(ws + 46 * M);               // 4 x 4.47 MiB slabs
    u16*   yn    = Hb;                                  // reuse after gemm0

    cvt_all_kernel<<<2048, 256, 0, stream>>>(H, Wq, Wk, Wv, Wo, gw,
                                             Hb, Wqb, Wkb, Wvb, Wob, gwb);

    gemm_nt<0><<<dim3(12, 64), 256, 0, stream>>>(Hb, Wqb, Wkb, Wvb, q, k, vt,
                                                 nullptr, nullptr, nullptr);
    akv_kernel<<<dim3(8, 64), 512, 0, stream>>>(q, k, vt, gwb, yn, kvpart);
    gemm_nt<1><<<dim3(8, 64), 256, 0, stream>>>(yn, Wob, nullptr, nullptr,
                                                nullptr, nullptr, nullptr, outf,
                                                kvpart, outf + (size_t)8388608);
}